// Round 7
// baseline (330.633 us; speedup 1.0000x reference)
//
#include <hip/hip_runtime.h>
#include <hip/hip_bf16.h>

#define TD 128    // feature dim, fixed by problem
#define WS 136    // padded W-LDS row stride in bf16 (272 B: 16B-aligned, bank-uniform for b128)
#define SC_T 8    // triples per scoring block (R4 lesson: LDS > 80KB -> 1 block/CU cliff)
#define BKT_SH 7  // 128 nodes per CSR bucket (NB = ceil(N/128) <= 1024 for N <= 131072)
#define NBLK 256  // partition blocks for hist/scat passes

typedef __attribute__((ext_vector_type(8))) short bf16x8;   // 8 bf16 = 4 VGPR (MFMA A/B frag)
typedef __attribute__((ext_vector_type(4))) float f32x4;    // MFMA C/D frag

static __device__ __forceinline__ unsigned short f2bf(float f) {
    unsigned int u = __float_as_uint(f);
    u += 0x7fffu + ((u >> 16) & 1u);   // round-to-nearest-even
    return (unsigned short)(u >> 16);
}
static __device__ __forceinline__ float bf2f(unsigned short h) {
    return __uint_as_float((unsigned int)h << 16);
}

// ================= atomic-free CSR build =================
// R3: global atomic RMWs hit a ~24 op/ns chip floor with ~32B/op HBM write-through; replaced
// by LDS-histogram multi-split (zero global atomics). R7: wsplit fused in as extra blocks.

// pass 1: per-block bucket histogram (+ relation histogram) + fused W transpose/bf16 split.
__global__ __launch_bounds__(256) void kc_hist(const int* __restrict__ ei, int* __restrict__ bh,
                                               const int* __restrict__ rel, int* __restrict__ rcount,
                                               const float* __restrict__ W1, const float* __restrict__ W2,
                                               unsigned short* __restrict__ Wt,
                                               int E_, int ES_, int NB, int chunk, int rchunk) {
    __shared__ int lh[1024];
    __shared__ int rh[16];
    int t = threadIdx.x, blk = blockIdx.x;
    if (blk >= NBLK) {   // fused wsplit: blocks NBLK..NBLK+63, bf16-hi only (R7: lo planes dropped)
        int idx = (blk - NBLK) * 256 + t;   // 0..16383 = k*128+n (coalesced read)
        int k = idx >> 7, n = idx & 127;
        Wt[n * 128 + k] = f2bf(W1[idx]);
        Wt[16384 + n * 128 + k] = f2bf(W2[idx]);
        return;
    }
    for (int j = t; j < NB; j += 256) lh[j] = 0;
    if (t < 16) rh[t] = 0;
    __syncthreads();
    int e0 = blk * chunk, e1 = min(E_, e0 + chunk);
    for (int e = e0 + t; e < e1; e += 256)
        atomicAdd(&lh[ei[E_ + e] >> BKT_SH], 1);   // LDS atomic
    int r0 = blk * rchunk, r1 = min(ES_, r0 + rchunk);
    for (int e = r0 + t; e < r1; e += 256)
        atomicAdd(&rh[rel[e]], 1);                 // LDS atomic
    __syncthreads();
    for (int j = t; j < NB; j += 256) bh[(size_t)j * NBLK + blk] = lh[j];
    if (t < 16 && rh[t]) atomicAdd(&rcount[t], rh[t]);   // fire-and-forget, 16/block
}

// pass 2a: per bucket, exclusive scan over the NBLK block counts (in place); tot[b] = bucket size
__global__ __launch_bounds__(64) void kc_scanA(int* __restrict__ bh, int* __restrict__ tot, int NB) {
    int b = blockIdx.x, l = threadIdx.x;
    int* row = bh + (size_t)b * NBLK;
    int run = 0;
#pragma unroll
    for (int g = 0; g < NBLK / 64; ++g) {
        int v = row[g * 64 + l];
        int x = v;
#pragma unroll
        for (int off = 1; off < 64; off <<= 1) {
            int y = __shfl_up(x, off);
            if (l >= off) x += y;
        }
        row[g * 64 + l] = run + x - v;   // exclusive within bucket
        run += __shfl(x, 63);
    }
    if (l == 0) tot[b] = run;
}

// pass 2b: single-block exclusive scan of bucket totals -> boff[0..NB], rowptr[N] = E.
// R7: relation-offset scan + cursor init folded in (rcount final since kc_hist).
__global__ __launch_bounds__(256) void kc_scanB(const int* __restrict__ tot, int* __restrict__ boff,
                                                int NB, int* __restrict__ rowptrN,
                                                const int* __restrict__ rcount, int* __restrict__ roff,
                                                int* __restrict__ chunkoff, int* __restrict__ cursor, int nr) {
    __shared__ int wsum[4];
    int t = threadIdx.x;
    int base = t * 4;
    int a0 = (base     < NB) ? tot[base]     : 0;
    int a1 = (base + 1 < NB) ? tot[base + 1] : 0;
    int a2 = (base + 2 < NB) ? tot[base + 2] : 0;
    int a3 = (base + 3 < NB) ? tot[base + 3] : 0;
    int s1 = a0 + a1, s2 = s1 + a2, tt = s2 + a3;
    int lane = t & 63, wv = t >> 6;
    int x = tt;
#pragma unroll
    for (int off = 1; off < 64; off <<= 1) {
        int y = __shfl_up(x, off);
        if (lane >= off) x += y;
    }
    if (lane == 63) wsum[wv] = x;
    __syncthreads();
    int woff = 0;
    for (int w = 0; w < wv; ++w) woff += wsum[w];
    int excl = woff + x - tt;
    if (base     < NB) boff[base]     = excl;
    if (base + 1 < NB) boff[base + 1] = excl + a0;
    if (base + 2 < NB) boff[base + 2] = excl + s1;
    if (base + 3 < NB) boff[base + 3] = excl + s2;
    if (t == 255) { boff[NB] = woff + x; *rowptrN = woff + x; }
    if (t == 0) {   // relation offsets (serial, nr <= 16)
        int run = 0, crun = 0;
        for (int r = 0; r < nr; ++r) {
            roff[r] = run; chunkoff[r] = crun; cursor[r] = run;
            run += rcount[r]; crun += (rcount[r] + SC_T - 1) / SC_T;
        }
        roff[nr] = run; chunkoff[nr] = crun;
    }
}

// pass 3: scatter edges into bucket-grouped ebuf, packed (src<<7)|(dst&127). LDS-atomic ranks.
__global__ __launch_bounds__(256) void kc_scat(const int* __restrict__ ei, const int* __restrict__ bh,
                                               const int* __restrict__ boff, int* __restrict__ ebuf,
                                               int E_, int NB, int chunk) {
    __shared__ int lh[1024];
    int t = threadIdx.x, blk = blockIdx.x;
    for (int j = t; j < NB; j += 256) lh[j] = 0;
    __syncthreads();
    int e0 = blk * chunk, e1 = min(E_, e0 + chunk);
    for (int e = e0 + t; e < e1; e += 256) {
        int s = ei[e];
        int d = ei[E_ + e];
        int b = d >> BKT_SH;
        int lr = atomicAdd(&lh[b], 1);   // LDS atomic: rank within (block, bucket)
        int slot = boff[b] + bh[(size_t)b * NBLK + blk] + lr;
        ebuf[slot] = (s << BKT_SH) | (d & ((1 << BKT_SH) - 1));
    }
}

// pass 4: one block per bucket -> exact per-node counting sort. Writes rowptr, dinv, esrc.
__global__ __launch_bounds__(256) void kc_build(const int* __restrict__ ebuf, const int* __restrict__ boff,
                                                int* __restrict__ rowptr, float* __restrict__ dinv,
                                                int* __restrict__ esrc, int n) {
    __shared__ int hist[128], excl[128], cur[128];
    __shared__ int w0;
    int b = blockIdx.x, t = threadIdx.x;
    int node0 = b << BKT_SH;
    int s = boff[b], e = boff[b + 1];
    if (t < 128) { hist[t] = 0; cur[t] = 0; }
    __syncthreads();
    for (int i = s + t; i < e; i += 256)
        atomicAdd(&hist[ebuf[i] & 127], 1);   // LDS atomic
    __syncthreads();
    // scan the 128 counts (waves 0,1 active; uniform syncs)
    int v = (t < 128) ? hist[t] : 0;
    int lane = t & 63, wv = t >> 6;
    int x = v;
#pragma unroll
    for (int off = 1; off < 64; off <<= 1) {
        int y = __shfl_up(x, off);
        if (lane >= off) x += y;
    }
    if (t == 63) w0 = x;
    __syncthreads();
    if (t < 128) {
        int ex = x - v + (wv == 1 ? w0 : 0);
        excl[t] = ex;
        int node = node0 + t;
        if (node < n) {
            rowptr[node] = s + ex;
            dinv[node] = (v > 0) ? 1.0f / sqrtf((float)v) : 0.0f;
        }
    }
    __syncthreads();
    for (int i = s + t; i < e; i += 256) {
        int p = ebuf[i];
        int loc = p & 127;
        int lr = atomicAdd(&cur[loc], 1);   // LDS atomic
        esrc[s + excl[loc] + lr] = p >> BKT_SH;
    }
}

// ---------------- MFMA GEMM v8: bf16-only, 34KB LDS -> 4 blocks/CU ----------------
// R7: the hi/lo split is pointless post-int8: lo-terms correct ~0.11% rel error vs the 0.57%
// int8 output quant we already accepted (quadrature 0.57->0.59%). Dropping both lo MFMA terms:
// 32 MFMA (was 96), W-LDS 34KB (was 68) -> 4 blocks/CU, staging halved.
__global__ __launch_bounds__(256, 4) void k_gemm(const float* __restrict__ X,
                                                 const unsigned short* __restrict__ Wth,
                                                 const float* __restrict__ scale,
                                                 unsigned char* __restrict__ out8,
                                                 float* __restrict__ scOut,
                                                 int nrows) {
    __shared__ __align__(16) unsigned short Wl[128 * WS];   // 34 KB; reused by epilogue transpose
    const int t = threadIdx.x;
    const int w = t >> 6;
    const int lane = t & 63;
    const int l15 = lane & 15;
    const int quad = lane >> 4;
    const int rbase = blockIdx.x * 64 + w * 16;   // wave's 16-row tile
    const int arow = rbase + l15;                 // this lane's A row
    const bool avalid = arow < nrows;

    // A: 8 float4 loads, issue immediately (independent of staging)
    float4 xa[4][2];
#pragma unroll
    for (int kc = 0; kc < 4; ++kc) {
        const float* src = X + (size_t)arow * TD + kc * 32 + quad * 8;
        xa[kc][0] = avalid ? *(const float4*)src       : make_float4(0.f, 0.f, 0.f, 0.f);
        xa[kc][1] = avalid ? *(const float4*)(src + 4) : make_float4(0.f, 0.f, 0.f, 0.f);
    }

    // stage W-hi -> padded LDS: 2048 uint4, 8 per thread
    {
        const uint4* gh = (const uint4*)Wth;
#pragma unroll
        for (int it = 0; it < 8; ++it) {
            int idx = t + it * 256;            // 0..2047
            int n = idx >> 4, kg = idx & 15;   // row n, k-group kg (8 bf16 each)
            uint4 vh = gh[idx];
            *(uint4*)&Wl[n * WS + kg * 8] = vh;
        }
    }

    // convert A to bf16 fragments while staging is in flight
    bf16x8 ah[4];
#pragma unroll
    for (int kc = 0; kc < 4; ++kc) {
#pragma unroll
        for (int j = 0; j < 8; ++j) {
            float v = (j < 4) ? ((const float*)&xa[kc][0])[j] : ((const float*)&xa[kc][1])[j - 4];
            ah[kc][j] = (short)f2bf(v);
        }
    }
    __syncthreads();

    f32x4 acc[8];
#pragma unroll
    for (int b = 0; b < 8; ++b) acc[b] = (f32x4){0.f, 0.f, 0.f, 0.f};

#pragma unroll
    for (int kc = 0; kc < 4; ++kc) {
        const int koff = kc * 32 + quad * 8;
#pragma unroll
        for (int b = 0; b < 8; ++b) {
            bf16x8 bh = *(const bf16x8*)&Wl[(b * 16 + l15) * WS + koff];
            acc[b] = __builtin_amdgcn_mfma_f32_16x16x32_bf16(ah[kc], bh, acc[b], 0, 0, 0);
        }
    }

    __syncthreads();   // all waves done reading Wl -> safe to reuse as transpose buffer

    // epilogue: m = acc*dinv; rowmax over 16 lanes; int8 quantize; LDS byte transpose
    {
        unsigned char* lds8 = (unsigned char*)&Wl[0];
        const int grow = rbase + quad * 4;        // multiple of 4; nrows % 4 == 0
        float4 s4 = make_float4(0.f, 0.f, 0.f, 0.f);
        if (grow < nrows) s4 = *(const float4*)&scale[grow];
        float rm[4];
#pragma unroll
        for (int j = 0; j < 4; ++j) {
            float sj = ((const float*)&s4)[j];
            float mx = 0.f;
#pragma unroll
            for (int b = 0; b < 8; ++b) {
                acc[b][j] *= sj;
                mx = fmaxf(mx, fabsf(acc[b][j]));
            }
            rm[j] = mx;
        }
#pragma unroll
        for (int m_ = 1; m_ < 16; m_ <<= 1)
#pragma unroll
            for (int j = 0; j < 4; ++j) rm[j] = fmaxf(rm[j], __shfl_xor(rm[j], m_));
        float inv[4];
#pragma unroll
        for (int j = 0; j < 4; ++j) inv[j] = rm[j] > 0.f ? 127.f / rm[j] : 0.f;
#pragma unroll
        for (int j = 0; j < 4; ++j) {
            int lrow = w * 16 + quad * 4 + j;
#pragma unroll
            for (int b = 0; b < 8; ++b) {
                int q = (int)rintf(acc[b][j] * inv[j]);
                lds8[lrow * 128 + b * 16 + l15] = (unsigned char)(signed char)q;
            }
        }
        if (l15 == 0 && grow < nrows)
            *(float4*)&scOut[grow] = make_float4(rm[0] * (1.f / 127.f), rm[1] * (1.f / 127.f),
                                                 rm[2] * (1.f / 127.f), rm[3] * (1.f / 127.f));
    }
    __syncthreads();
    {   // linear coalesced copy: 2048 dwords (64 rows x 128 B)
        const unsigned int* lds32 = (const unsigned int*)&Wl[0];
        unsigned int* g32 = (unsigned int*)out8;
#pragma unroll
        for (int k = 0; k < 8; ++k) {
            int idx = t + k * 256;
            int row = blockIdx.x * 64 + (idx >> 5);
            if (row < nrows) g32[(size_t)blockIdx.x * 2048 + idx] = lds32[idx];
        }
    }
}

// ---------------- CSR aggregation v2: int8 gather + per-row scale, f32 accumulate ----------------
// R6 counters: FETCH 86MB ~= the 12.8MB x 8-XCD compulsory bound; at the random-128B floor.
// Left byte-identical.
#define ACCI8(p, u, s) \
    p##0 = fmaf(s, (float)(signed char)(u.x      ), p##0); \
    p##1 = fmaf(s, (float)(signed char)(u.x >>  8), p##1); \
    p##2 = fmaf(s, (float)(signed char)(u.x >> 16), p##2); \
    p##3 = fmaf(s, (float)(signed char)(u.x >> 24), p##3); \
    p##4 = fmaf(s, (float)(signed char)(u.y      ), p##4); \
    p##5 = fmaf(s, (float)(signed char)(u.y >>  8), p##5); \
    p##6 = fmaf(s, (float)(signed char)(u.y >> 16), p##6); \
    p##7 = fmaf(s, (float)(signed char)(u.y >> 24), p##7);

__global__ __launch_bounds__(256) void k_agg(const unsigned char* __restrict__ hs8, const float* __restrict__ sc,
                                             const int* __restrict__ rowptr, const int* __restrict__ esrc,
                                             const float* __restrict__ dinv, const float* __restrict__ bias,
                                             float* __restrict__ out, int n, int relu) {
    int node = blockIdx.x * 16 + (threadIdx.x >> 4);
    int lane = threadIdx.x & 15;
    if (node >= n) return;
    int s = rowptr[node], e = rowptr[node + 1];
    const uint2* h8 = (const uint2*)hs8;   // 16 lanes x 8B = one 128B int8 row
    float a0 = 0.f, a1 = 0.f, a2 = 0.f, a3 = 0.f, a4 = 0.f, a5 = 0.f, a6 = 0.f, a7 = 0.f;
    float c0 = 0.f, c1 = 0.f, c2 = 0.f, c3 = 0.f, c4 = 0.f, c5 = 0.f, c6 = 0.f, c7 = 0.f;
    int i = s;
    for (; i + 4 <= e; i += 4) {
        int s0 = esrc[i], s1 = esrc[i + 1], s2 = esrc[i + 2], s3 = esrc[i + 3];
        uint2 u0 = h8[(size_t)s0 * 16 + lane];
        uint2 u1 = h8[(size_t)s1 * 16 + lane];
        uint2 u2 = h8[(size_t)s2 * 16 + lane];
        uint2 u3 = h8[(size_t)s3 * 16 + lane];
        float f0 = sc[s0], f1 = sc[s1], f2 = sc[s2], f3 = sc[s3];
        ACCI8(a, u0, f0)
        ACCI8(c, u1, f1)
        ACCI8(a, u2, f2)
        ACCI8(c, u3, f3)
    }
    for (; i < e; ++i) {
        int s0 = esrc[i];
        uint2 u = h8[(size_t)s0 * 16 + lane];
        float f = sc[s0];
        ACCI8(a, u, f)
    }
    a0 += c0; a1 += c1; a2 += c2; a3 += c3;
    a4 += c4; a5 += c5; a6 += c6; a7 += c7;
    float di = dinv[node];
    float4 b0 = ((const float4*)bias)[lane * 2];
    float4 b1 = ((const float4*)bias)[lane * 2 + 1];
    float o0 = fmaf(di, a0, b0.x);
    float o1 = fmaf(di, a1, b0.y);
    float o2 = fmaf(di, a2, b0.z);
    float o3 = fmaf(di, a3, b0.w);
    float o4 = fmaf(di, a4, b1.x);
    float o5 = fmaf(di, a5, b1.y);
    float o6 = fmaf(di, a6, b1.z);
    float o7 = fmaf(di, a7, b1.w);
    if (relu) {
        o0 = fmaxf(o0, 0.f); o1 = fmaxf(o1, 0.f); o2 = fmaxf(o2, 0.f); o3 = fmaxf(o3, 0.f);
        o4 = fmaxf(o4, 0.f); o5 = fmaxf(o5, 0.f); o6 = fmaxf(o6, 0.f); o7 = fmaxf(o7, 0.f);
    }
    ((float4*)out)[(size_t)node * 32 + lane * 2]     = make_float4(o0, o1, o2, o3);
    ((float4*)out)[(size_t)node * 32 + lane * 2 + 1] = make_float4(o4, o5, o6, o7);
}

__global__ __launch_bounds__(256) void k_bucket(const int* __restrict__ rel, int* __restrict__ cursor,
                                                int* __restrict__ eidx, int es) {
    __shared__ int lh[16];
    __shared__ int lbase[16];
    int t = threadIdx.x;
    if (t < 16) lh[t] = 0;
    __syncthreads();
    int r[4], lr[4];
#pragma unroll
    for (int i = 0; i < 4; ++i) {
        int e = blockIdx.x * 1024 + i * 256 + t;
        if (e < es) {
            r[i] = rel[e];
            lr[i] = atomicAdd(&lh[r[i]], 1);   // LDS atomic: intra-block rank
        } else r[i] = -1;
    }
    __syncthreads();
    if (t < 16) lbase[t] = lh[t] ? atomicAdd(&cursor[t], lh[t]) : 0;   // reserve range
    __syncthreads();
#pragma unroll
    for (int i = 0; i < 4; ++i)
        if (r[i] >= 0) eidx[lbase[r[i]] + lr[i]] = blockIdx.x * 1024 + i * 256 + t;
}

// ---------------- batched scoring v4: zh double-buffered, zt in registers ----------------
// R7: zt moved from LDS to per-thread registers (each thread only needs its 4 columns per
// triple; loads issued at compute start, consumed after the 512-FMA loop). zh+eids double-
// buffered (stage next chunk during current compute, one barrier/chunk; red[] also dbuf'd
// to kill the cross-wave race). LDS 72.3KB -> still 2 blocks/CU. W[r] cached across
// same-relation chunks (R5); extra barrier only on relation change (~3% of steps).
__global__ __launch_bounds__(256) void k_score_r(const float* __restrict__ z, const float* __restrict__ relW,
                                                 const int* __restrict__ eidx, const int* __restrict__ head,
                                                 const int* __restrict__ tail, const int* __restrict__ roff,
                                                 const int* __restrict__ chunkoff, float* __restrict__ out,
                                                 int R_, int cpb) {
    __shared__ __align__(16) float Wl[TD * TD];        // 64 KB
    __shared__ __align__(16) float zhL[2][SC_T * TD];  // 8 KB
    __shared__ int eids[2][SC_T];
    __shared__ float red[2][4][SC_T];
    const int t = threadIdx.x;
    const int nch = chunkoff[R_];
    int b0 = (int)blockIdx.x * cpb;
    const int bend = min(nch, b0 + cpb);
    if (b0 >= bend) return;   // uniform exit, before any barrier

    auto stage_z = [&](int b, int rr, int buf) {
        int base = roff[rr] + (b - chunkoff[rr]) * SC_T;
        int nt2 = min(SC_T, roff[rr + 1] - base);
        int tt = t >> 5, c4 = t & 31;
        if (t < SC_T) eids[buf][t] = (t < nt2) ? eidx[base + t] : -1;
        int e = (tt < nt2) ? eidx[base + tt] : -1;   // direct global read: no intra-stage barrier
        float4 vh = make_float4(0.f, 0.f, 0.f, 0.f);
        if (e >= 0) vh = ((const float4*)(z + (size_t)head[e] * TD))[c4];
        ((float4*)(zhL[buf] + tt * TD))[c4] = vh;
    };
    auto stage_W = [&](int rr) {
        const float4* W4 = (const float4*)(relW + (size_t)rr * TD * TD);
        float4* Wl4 = (float4*)Wl;
#pragma unroll
        for (int i = 0; i < 16; ++i) Wl4[t + i * 256] = W4[t + i * 256];
    };

    int r = 0;
    while (chunkoff[r + 1] <= b0) ++r;
    stage_z(b0, r, 0);
    stage_W(r);
    __syncthreads();
    int cur = 0;
    const int c  = (t & 31) * 4;    // cols c..c+3
    const int i0 = (t >> 5) * 16;   // 16-row i segment
    for (int b = b0; b < bend; ++b) {
        int rn = r;
        const bool havenext = (b + 1 < bend);
        if (havenext) while (chunkoff[rn + 1] <= b + 1) ++rn;
        const bool sameW = havenext && (rn == r);
        if (sameW) stage_z(b + 1, rn, cur ^ 1);   // prefetch into other buffer, no barrier

        // zt gather into registers (issued early, consumed after the FMA loop)
        float4 ztr[SC_T];
#pragma unroll
        for (int u = 0; u < SC_T; ++u) {
            int e = eids[cur][u];
            ztr[u] = make_float4(0.f, 0.f, 0.f, 0.f);
            if (e >= 0) ztr[u] = *(const float4*)(z + (size_t)tail[e] * TD + c);
        }
        float4 acc[SC_T];
#pragma unroll
        for (int u = 0; u < SC_T; ++u) acc[u] = make_float4(0.f, 0.f, 0.f, 0.f);
        const float* zh = zhL[cur];
#pragma unroll 4
        for (int i = i0; i < i0 + 16; ++i) {
            float4 wv = *(const float4*)&Wl[i * TD + c];
#pragma unroll
            for (int u = 0; u < SC_T; ++u) {
                float h = zh[u * TD + i];
                acc[u].x = fmaf(h, wv.x, acc[u].x);
                acc[u].y = fmaf(h, wv.y, acc[u].y);
                acc[u].z = fmaf(h, wv.z, acc[u].z);
                acc[u].w = fmaf(h, wv.w, acc[u].w);
            }
        }
        float pth[SC_T];
#pragma unroll
        for (int u = 0; u < SC_T; ++u)
            pth[u] = acc[u].x * ztr[u].x + acc[u].y * ztr[u].y + acc[u].z * ztr[u].z + acc[u].w * ztr[u].w;
#pragma unroll
        for (int off = 32; off > 0; off >>= 1)
#pragma unroll
            for (int u = 0; u < SC_T; ++u) pth[u] += __shfl_down(pth[u], off);
        if ((t & 63) == 0) {
            int wv2 = t >> 6;
#pragma unroll
            for (int u = 0; u < SC_T; ++u) red[cur][wv2][u] = pth[u];
        }
        __syncthreads();   // red+staged-buffer visible; the one barrier per chunk
        if (t < SC_T) {
            int e = eids[cur][t];
            if (e >= 0) out[e] = red[cur][0][t] + red[cur][1][t] + red[cur][2][t] + red[cur][3][t];
        }
        if (havenext && !sameW) {   // relation change: Wl free (compute done pre-barrier)
            stage_z(b + 1, rn, cur ^ 1);
            stage_W(rn);
            __syncthreads();
        }
        r = rn; cur ^= 1;
    }
}

extern "C" void kernel_launch(void* const* d_in, const int* in_sizes, int n_in,
                              void* d_out, int out_size, void* d_ws, size_t ws_size,
                              hipStream_t stream) {
    const float* x0   = (const float*)d_in[0];
    const float* W1   = (const float*)d_in[1];
    const float* b1   = (const float*)d_in[2];
    const float* W2   = (const float*)d_in[3];
    const float* b2   = (const float*)d_in[4];
    const float* relW = (const float*)d_in[5];
    const int*   ei   = (const int*)d_in[6];
    const int*   rel  = (const int*)d_in[7];
    const int*   head = (const int*)d_in[8];
    const int*   tail = (const int*)d_in[9];
    float* outp = (float*)d_out;

    const int N_  = in_sizes[0] / TD;
    const int E_  = in_sizes[6] / 2;
    const int ES_ = in_sizes[7];
    const int R_  = in_sizes[5] / (TD * TD);
    const int ntiles64 = (N_ + 63) / 64;
    const int NB    = (N_ + (1 << BKT_SH) - 1) >> BKT_SH;   // <= 1024 for N <= 131072
    const int chunk  = (E_ + NBLK - 1) / NBLK;
    const int rchunk = (ES_ + NBLK - 1) / NBLK;
    const int maxch  = (ES_ + SC_T - 1) / SC_T + R_;        // upper bound on chunk count
    const int sgrid  = maxch < 512 ? maxch : 512;           // 2 blocks/CU
    const int cpb    = (maxch + sgrid - 1) / sgrid;         // chunks per block (contiguous)

    char* p = (char*)d_ws;
    auto alloc = [&](size_t bytes) { char* r = p; p += (bytes + 255) & ~(size_t)255; return r; };
    float*          dinv   = (float*)         alloc((size_t)N_ * 4);
    int*            rowptr = (int*)           alloc(((size_t)N_ + 1) * 4);
    int*            bh     = (int*)           alloc((size_t)NB * NBLK * 4);
    int*            tot    = (int*)           alloc((size_t)NB * 4);
    int*            boff   = (int*)           alloc(((size_t)NB + 1) * 4);
    int*            esrc   = (int*)           alloc((size_t)E_ * 4);
    unsigned short* Wt     = (unsigned short*)alloc((size_t)2 * 16384 * 2);   // W1h^T, W2h^T
    int*            rcount = (int*)           alloc((size_t)R_ * 4);
    int*            roff   = (int*)           alloc(((size_t)R_ + 1) * 4);
    int*            chkoff = (int*)           alloc(((size_t)R_ + 1) * 4);
    int*            cursor = (int*)           alloc((size_t)R_ * 4);
    int*            eidx   = (int*)           alloc((size_t)ES_ * 4);
    unsigned char*  bufA   = (unsigned char*) alloc((size_t)N_ * TD);         // int8 messages
    float*          sc     = (float*)         alloc((size_t)N_ * 4);          // per-row scales
    float*          bufB   = (float*)         alloc((size_t)N_ * TD * 4);     // f32 conv out
    int*            ebuf   = (int*)bufA;   // alias: dead before first k_gemm writes bufA (E*4 <= N*TD)

    hipMemsetAsync(rcount, 0, (size_t)R_ * 4, stream);

    // atomic-free CSR: hist(+rel histo, +wsplit) -> scanA -> scanB(+roff) -> scatter -> build
    kc_hist <<<NBLK + 64, 256, 0, stream>>>(ei, bh, rel, rcount, W1, W2, Wt, E_, ES_, NB, chunk, rchunk);
    kc_scanA<<<NB, 64, 0, stream>>>(bh, tot, NB);
    kc_scanB<<<1, 256, 0, stream>>>(tot, boff, NB, rowptr + N_, rcount, roff, chkoff, cursor, R_);
    kc_scat <<<NBLK, 256, 0, stream>>>(ei, bh, boff, ebuf, E_, NB, chunk);
    kc_build<<<NB, 256, 0, stream>>>(ebuf, boff, rowptr, dinv, esrc, N_);

    k_bucket<<<(ES_ + 1023) / 1024, 256, 0, stream>>>(rel, cursor, eidx, ES_);

    // conv1: bufA,sc = int8(dinv * (x0 @ W1)); bufB = relu(dinv*agg(bufA*sc) + b1)
    k_gemm<<<ntiles64, 256, 0, stream>>>(x0, Wt, dinv, bufA, sc, N_);
    k_agg <<<(N_ + 15) / 16, 256, 0, stream>>>(bufA, sc, rowptr, esrc, dinv, b1, bufB, N_, 1);
    // conv2: bufA,sc = int8(dinv * (bufB @ W2)); bufB = dinv*agg(bufA*sc) + b2  (= z)
    k_gemm<<<ntiles64, 256, 0, stream>>>(bufB, Wt + 16384, dinv, bufA, sc, N_);
    k_agg <<<(N_ + 15) / 16, 256, 0, stream>>>(bufA, sc, rowptr, esrc, dinv, b2, bufB, N_, 0);

    // scoring: contiguous chunk ranges, W cached across same-relation chunks
    k_score_r<<<sgrid, 256, 0, stream>>>(bufB, relW, eidx, head, tail,
                                         roff, chkoff, outp, R_, cpb);
}

// Round 8
// 305.302 us; speedup vs baseline: 1.0830x; 1.0830x over previous
//
#include <hip/hip_runtime.h>
#include <hip/hip_bf16.h>

#define TD 128    // feature dim, fixed by problem
#define WS 136    // padded W-LDS row stride in bf16 (272 B: 16B-aligned, bank-uniform for b128)
#define SC_T 8    // triples per scoring block (R4 lesson: LDS > 80KB -> 1 block/CU cliff)
#define BKT_SH 7  // 128 nodes per CSR bucket (NB = ceil(N/128) <= 1024 for N <= 131072)
#define NBLK 256  // partition blocks for hist/scat passes

typedef __attribute__((ext_vector_type(8))) short bf16x8;   // 8 bf16 = 4 VGPR (MFMA A/B frag)
typedef __attribute__((ext_vector_type(4))) float f32x4;    // MFMA C/D frag

static __device__ __forceinline__ unsigned short f2bf(float f) {
    unsigned int u = __float_as_uint(f);
    u += 0x7fffu + ((u >> 16) & 1u);   // round-to-nearest-even
    return (unsigned short)(u >> 16);
}
static __device__ __forceinline__ float bf2f(unsigned short h) {
    return __uint_as_float((unsigned int)h << 16);
}

// ================= atomic-free CSR build =================
// R3: global atomic RMWs hit a ~24 op/ns chip floor with ~32B/op HBM write-through; replaced
// by LDS-histogram multi-split (zero global atomics). R7: wsplit fused in as extra blocks.

// pass 1: per-block bucket histogram (+ relation histogram) + fused W transpose/bf16 split.
__global__ __launch_bounds__(256) void kc_hist(const int* __restrict__ ei, int* __restrict__ bh,
                                               const int* __restrict__ rel, int* __restrict__ rcount,
                                               const float* __restrict__ W1, const float* __restrict__ W2,
                                               unsigned short* __restrict__ Wt,
                                               int E_, int ES_, int NB, int chunk, int rchunk) {
    __shared__ int lh[1024];
    __shared__ int rh[16];
    int t = threadIdx.x, blk = blockIdx.x;
    if (blk >= NBLK) {   // fused wsplit: blocks NBLK..NBLK+63, bf16-hi only (R7: lo planes dropped)
        int idx = (blk - NBLK) * 256 + t;   // 0..16383 = k*128+n (coalesced read)
        int k = idx >> 7, n = idx & 127;
        Wt[n * 128 + k] = f2bf(W1[idx]);
        Wt[16384 + n * 128 + k] = f2bf(W2[idx]);
        return;
    }
    for (int j = t; j < NB; j += 256) lh[j] = 0;
    if (t < 16) rh[t] = 0;
    __syncthreads();
    int e0 = blk * chunk, e1 = min(E_, e0 + chunk);
    for (int e = e0 + t; e < e1; e += 256)
        atomicAdd(&lh[ei[E_ + e] >> BKT_SH], 1);   // LDS atomic
    int r0 = blk * rchunk, r1 = min(ES_, r0 + rchunk);
    for (int e = r0 + t; e < r1; e += 256)
        atomicAdd(&rh[rel[e]], 1);                 // LDS atomic
    __syncthreads();
    for (int j = t; j < NB; j += 256) bh[(size_t)j * NBLK + blk] = lh[j];
    if (t < 16 && rh[t]) atomicAdd(&rcount[t], rh[t]);   // fire-and-forget, 16/block
}

// pass 2a: per bucket, exclusive scan over the NBLK block counts (in place); tot[b] = bucket size
__global__ __launch_bounds__(64) void kc_scanA(int* __restrict__ bh, int* __restrict__ tot, int NB) {
    int b = blockIdx.x, l = threadIdx.x;
    int* row = bh + (size_t)b * NBLK;
    int run = 0;
#pragma unroll
    for (int g = 0; g < NBLK / 64; ++g) {
        int v = row[g * 64 + l];
        int x = v;
#pragma unroll
        for (int off = 1; off < 64; off <<= 1) {
            int y = __shfl_up(x, off);
            if (l >= off) x += y;
        }
        row[g * 64 + l] = run + x - v;   // exclusive within bucket
        run += __shfl(x, 63);
    }
    if (l == 0) tot[b] = run;
}

// pass 2b: single-block exclusive scan of bucket totals -> boff[0..NB], rowptr[N] = E.
// R7: relation-offset scan + cursor init folded in (rcount final since kc_hist).
__global__ __launch_bounds__(256) void kc_scanB(const int* __restrict__ tot, int* __restrict__ boff,
                                                int NB, int* __restrict__ rowptrN,
                                                const int* __restrict__ rcount, int* __restrict__ roff,
                                                int* __restrict__ chunkoff, int* __restrict__ cursor, int nr) {
    __shared__ int wsum[4];
    int t = threadIdx.x;
    int base = t * 4;
    int a0 = (base     < NB) ? tot[base]     : 0;
    int a1 = (base + 1 < NB) ? tot[base + 1] : 0;
    int a2 = (base + 2 < NB) ? tot[base + 2] : 0;
    int a3 = (base + 3 < NB) ? tot[base + 3] : 0;
    int s1 = a0 + a1, s2 = s1 + a2, tt = s2 + a3;
    int lane = t & 63, wv = t >> 6;
    int x = tt;
#pragma unroll
    for (int off = 1; off < 64; off <<= 1) {
        int y = __shfl_up(x, off);
        if (lane >= off) x += y;
    }
    if (lane == 63) wsum[wv] = x;
    __syncthreads();
    int woff = 0;
    for (int w = 0; w < wv; ++w) woff += wsum[w];
    int excl = woff + x - tt;
    if (base     < NB) boff[base]     = excl;
    if (base + 1 < NB) boff[base + 1] = excl + a0;
    if (base + 2 < NB) boff[base + 2] = excl + s1;
    if (base + 3 < NB) boff[base + 3] = excl + s2;
    if (t == 255) { boff[NB] = woff + x; *rowptrN = woff + x; }
    if (t == 0) {   // relation offsets (serial, nr <= 16)
        int run = 0, crun = 0;
        for (int r = 0; r < nr; ++r) {
            roff[r] = run; chunkoff[r] = crun; cursor[r] = run;
            run += rcount[r]; crun += (rcount[r] + SC_T - 1) / SC_T;
        }
        roff[nr] = run; chunkoff[nr] = crun;
    }
}

// pass 3: scatter edges into bucket-grouped ebuf, packed (src<<7)|(dst&127). LDS-atomic ranks.
__global__ __launch_bounds__(256) void kc_scat(const int* __restrict__ ei, const int* __restrict__ bh,
                                               const int* __restrict__ boff, int* __restrict__ ebuf,
                                               int E_, int NB, int chunk) {
    __shared__ int lh[1024];
    int t = threadIdx.x, blk = blockIdx.x;
    for (int j = t; j < NB; j += 256) lh[j] = 0;
    __syncthreads();
    int e0 = blk * chunk, e1 = min(E_, e0 + chunk);
    for (int e = e0 + t; e < e1; e += 256) {
        int s = ei[e];
        int d = ei[E_ + e];
        int b = d >> BKT_SH;
        int lr = atomicAdd(&lh[b], 1);   // LDS atomic: rank within (block, bucket)
        int slot = boff[b] + bh[(size_t)b * NBLK + blk] + lr;
        ebuf[slot] = (s << BKT_SH) | (d & ((1 << BKT_SH) - 1));
    }
}

// pass 4: one block per bucket -> exact per-node counting sort. Writes rowptr, dinv, esrc.
__global__ __launch_bounds__(256) void kc_build(const int* __restrict__ ebuf, const int* __restrict__ boff,
                                                int* __restrict__ rowptr, float* __restrict__ dinv,
                                                int* __restrict__ esrc, int n) {
    __shared__ int hist[128], excl[128], cur[128];
    __shared__ int w0;
    int b = blockIdx.x, t = threadIdx.x;
    int node0 = b << BKT_SH;
    int s = boff[b], e = boff[b + 1];
    if (t < 128) { hist[t] = 0; cur[t] = 0; }
    __syncthreads();
    for (int i = s + t; i < e; i += 256)
        atomicAdd(&hist[ebuf[i] & 127], 1);   // LDS atomic
    __syncthreads();
    // scan the 128 counts (waves 0,1 active; uniform syncs)
    int v = (t < 128) ? hist[t] : 0;
    int lane = t & 63, wv = t >> 6;
    int x = v;
#pragma unroll
    for (int off = 1; off < 64; off <<= 1) {
        int y = __shfl_up(x, off);
        if (lane >= off) x += y;
    }
    if (t == 63) w0 = x;
    __syncthreads();
    if (t < 128) {
        int ex = x - v + (wv == 1 ? w0 : 0);
        excl[t] = ex;
        int node = node0 + t;
        if (node < n) {
            rowptr[node] = s + ex;
            dinv[node] = (v > 0) ? 1.0f / sqrtf((float)v) : 0.0f;
        }
    }
    __syncthreads();
    for (int i = s + t; i < e; i += 256) {
        int p = ebuf[i];
        int loc = p & 127;
        int lr = atomicAdd(&cur[loc], 1);   // LDS atomic
        esrc[s + excl[loc] + lr] = p >> BKT_SH;
    }
}

// ---------------- MFMA GEMM v8: bf16-only, 34KB LDS -> 4 blocks/CU ----------------
// R7: the hi/lo split is pointless post-int8: lo-terms correct ~0.11% rel error vs the 0.57%
// int8 output quant we already accepted. 32 MFMA (was 96), W-LDS 34KB -> 4 blocks/CU.
// R7 bench validated: ~15us total gain vs v7.
__global__ __launch_bounds__(256, 4) void k_gemm(const float* __restrict__ X,
                                                 const unsigned short* __restrict__ Wth,
                                                 const float* __restrict__ scale,
                                                 unsigned char* __restrict__ out8,
                                                 float* __restrict__ scOut,
                                                 int nrows) {
    __shared__ __align__(16) unsigned short Wl[128 * WS];   // 34 KB; reused by epilogue transpose
    const int t = threadIdx.x;
    const int w = t >> 6;
    const int lane = t & 63;
    const int l15 = lane & 15;
    const int quad = lane >> 4;
    const int rbase = blockIdx.x * 64 + w * 16;   // wave's 16-row tile
    const int arow = rbase + l15;                 // this lane's A row
    const bool avalid = arow < nrows;

    // A: 8 float4 loads, issue immediately (independent of staging)
    float4 xa[4][2];
#pragma unroll
    for (int kc = 0; kc < 4; ++kc) {
        const float* src = X + (size_t)arow * TD + kc * 32 + quad * 8;
        xa[kc][0] = avalid ? *(const float4*)src       : make_float4(0.f, 0.f, 0.f, 0.f);
        xa[kc][1] = avalid ? *(const float4*)(src + 4) : make_float4(0.f, 0.f, 0.f, 0.f);
    }

    // stage W-hi -> padded LDS: 2048 uint4, 8 per thread
    {
        const uint4* gh = (const uint4*)Wth;
#pragma unroll
        for (int it = 0; it < 8; ++it) {
            int idx = t + it * 256;            // 0..2047
            int n = idx >> 4, kg = idx & 15;   // row n, k-group kg (8 bf16 each)
            uint4 vh = gh[idx];
            *(uint4*)&Wl[n * WS + kg * 8] = vh;
        }
    }

    // convert A to bf16 fragments while staging is in flight
    bf16x8 ah[4];
#pragma unroll
    for (int kc = 0; kc < 4; ++kc) {
#pragma unroll
        for (int j = 0; j < 8; ++j) {
            float v = (j < 4) ? ((const float*)&xa[kc][0])[j] : ((const float*)&xa[kc][1])[j - 4];
            ah[kc][j] = (short)f2bf(v);
        }
    }
    __syncthreads();

    f32x4 acc[8];
#pragma unroll
    for (int b = 0; b < 8; ++b) acc[b] = (f32x4){0.f, 0.f, 0.f, 0.f};

#pragma unroll
    for (int kc = 0; kc < 4; ++kc) {
        const int koff = kc * 32 + quad * 8;
#pragma unroll
        for (int b = 0; b < 8; ++b) {
            bf16x8 bh = *(const bf16x8*)&Wl[(b * 16 + l15) * WS + koff];
            acc[b] = __builtin_amdgcn_mfma_f32_16x16x32_bf16(ah[kc], bh, acc[b], 0, 0, 0);
        }
    }

    __syncthreads();   // all waves done reading Wl -> safe to reuse as transpose buffer

    // epilogue: m = acc*dinv; rowmax over 16 lanes; int8 quantize; LDS byte transpose
    {
        unsigned char* lds8 = (unsigned char*)&Wl[0];
        const int grow = rbase + quad * 4;        // multiple of 4; nrows % 4 == 0
        float4 s4 = make_float4(0.f, 0.f, 0.f, 0.f);
        if (grow < nrows) s4 = *(const float4*)&scale[grow];
        float rm[4];
#pragma unroll
        for (int j = 0; j < 4; ++j) {
            float sj = ((const float*)&s4)[j];
            float mx = 0.f;
#pragma unroll
            for (int b = 0; b < 8; ++b) {
                acc[b][j] *= sj;
                mx = fmaxf(mx, fabsf(acc[b][j]));
            }
            rm[j] = mx;
        }
#pragma unroll
        for (int m_ = 1; m_ < 16; m_ <<= 1)
#pragma unroll
            for (int j = 0; j < 4; ++j) rm[j] = fmaxf(rm[j], __shfl_xor(rm[j], m_));
        float inv[4];
#pragma unroll
        for (int j = 0; j < 4; ++j) inv[j] = rm[j] > 0.f ? 127.f / rm[j] : 0.f;
#pragma unroll
        for (int j = 0; j < 4; ++j) {
            int lrow = w * 16 + quad * 4 + j;
#pragma unroll
            for (int b = 0; b < 8; ++b) {
                int q = (int)rintf(acc[b][j] * inv[j]);
                lds8[lrow * 128 + b * 16 + l15] = (unsigned char)(signed char)q;
            }
        }
        if (l15 == 0 && grow < nrows)
            *(float4*)&scOut[grow] = make_float4(rm[0] * (1.f / 127.f), rm[1] * (1.f / 127.f),
                                                 rm[2] * (1.f / 127.f), rm[3] * (1.f / 127.f));
    }
    __syncthreads();
    {   // linear coalesced copy: 2048 dwords (64 rows x 128 B)
        const unsigned int* lds32 = (const unsigned int*)&Wl[0];
        unsigned int* g32 = (unsigned int*)out8;
#pragma unroll
        for (int k = 0; k < 8; ++k) {
            int idx = t + k * 256;
            int row = blockIdx.x * 64 + (idx >> 5);
            if (row < nrows) g32[(size_t)blockIdx.x * 2048 + idx] = lds32[idx];
        }
    }
}

// ---------------- CSR aggregation v2: int8 gather + per-row scale, f32 accumulate ----------------
// R6 counters: FETCH 86MB ~= the 12.8MB x 8-XCD compulsory bound; at the random-128B floor.
// Left byte-identical.
#define ACCI8(p, u, s) \
    p##0 = fmaf(s, (float)(signed char)(u.x      ), p##0); \
    p##1 = fmaf(s, (float)(signed char)(u.x >>  8), p##1); \
    p##2 = fmaf(s, (float)(signed char)(u.x >> 16), p##2); \
    p##3 = fmaf(s, (float)(signed char)(u.x >> 24), p##3); \
    p##4 = fmaf(s, (float)(signed char)(u.y      ), p##4); \
    p##5 = fmaf(s, (float)(signed char)(u.y >>  8), p##5); \
    p##6 = fmaf(s, (float)(signed char)(u.y >> 16), p##6); \
    p##7 = fmaf(s, (float)(signed char)(u.y >> 24), p##7);

__global__ __launch_bounds__(256) void k_agg(const unsigned char* __restrict__ hs8, const float* __restrict__ sc,
                                             const int* __restrict__ rowptr, const int* __restrict__ esrc,
                                             const float* __restrict__ dinv, const float* __restrict__ bias,
                                             float* __restrict__ out, int n, int relu) {
    int node = blockIdx.x * 16 + (threadIdx.x >> 4);
    int lane = threadIdx.x & 15;
    if (node >= n) return;
    int s = rowptr[node], e = rowptr[node + 1];
    const uint2* h8 = (const uint2*)hs8;   // 16 lanes x 8B = one 128B int8 row
    float a0 = 0.f, a1 = 0.f, a2 = 0.f, a3 = 0.f, a4 = 0.f, a5 = 0.f, a6 = 0.f, a7 = 0.f;
    float c0 = 0.f, c1 = 0.f, c2 = 0.f, c3 = 0.f, c4 = 0.f, c5 = 0.f, c6 = 0.f, c7 = 0.f;
    int i = s;
    for (; i + 4 <= e; i += 4) {
        int s0 = esrc[i], s1 = esrc[i + 1], s2 = esrc[i + 2], s3 = esrc[i + 3];
        uint2 u0 = h8[(size_t)s0 * 16 + lane];
        uint2 u1 = h8[(size_t)s1 * 16 + lane];
        uint2 u2 = h8[(size_t)s2 * 16 + lane];
        uint2 u3 = h8[(size_t)s3 * 16 + lane];
        float f0 = sc[s0], f1 = sc[s1], f2 = sc[s2], f3 = sc[s3];
        ACCI8(a, u0, f0)
        ACCI8(c, u1, f1)
        ACCI8(a, u2, f2)
        ACCI8(c, u3, f3)
    }
    for (; i < e; ++i) {
        int s0 = esrc[i];
        uint2 u = h8[(size_t)s0 * 16 + lane];
        float f = sc[s0];
        ACCI8(a, u, f)
    }
    a0 += c0; a1 += c1; a2 += c2; a3 += c3;
    a4 += c4; a5 += c5; a6 += c6; a7 += c7;
    float di = dinv[node];
    float4 b0 = ((const float4*)bias)[lane * 2];
    float4 b1 = ((const float4*)bias)[lane * 2 + 1];
    float o0 = fmaf(di, a0, b0.x);
    float o1 = fmaf(di, a1, b0.y);
    float o2 = fmaf(di, a2, b0.z);
    float o3 = fmaf(di, a3, b0.w);
    float o4 = fmaf(di, a4, b1.x);
    float o5 = fmaf(di, a5, b1.y);
    float o6 = fmaf(di, a6, b1.z);
    float o7 = fmaf(di, a7, b1.w);
    if (relu) {
        o0 = fmaxf(o0, 0.f); o1 = fmaxf(o1, 0.f); o2 = fmaxf(o2, 0.f); o3 = fmaxf(o3, 0.f);
        o4 = fmaxf(o4, 0.f); o5 = fmaxf(o5, 0.f); o6 = fmaxf(o6, 0.f); o7 = fmaxf(o7, 0.f);
    }
    ((float4*)out)[(size_t)node * 32 + lane * 2]     = make_float4(o0, o1, o2, o3);
    ((float4*)out)[(size_t)node * 32 + lane * 2 + 1] = make_float4(o4, o5, o6, o7);
}

__global__ __launch_bounds__(256) void k_bucket(const int* __restrict__ rel, int* __restrict__ cursor,
                                                int* __restrict__ eidx, int es) {
    __shared__ int lh[16];
    __shared__ int lbase[16];
    int t = threadIdx.x;
    if (t < 16) lh[t] = 0;
    __syncthreads();
    int r[4], lr[4];
#pragma unroll
    for (int i = 0; i < 4; ++i) {
        int e = blockIdx.x * 1024 + i * 256 + t;
        if (e < es) {
            r[i] = rel[e];
            lr[i] = atomicAdd(&lh[r[i]], 1);   // LDS atomic: intra-block rank
        } else r[i] = -1;
    }
    __syncthreads();
    if (t < 16) lbase[t] = lh[t] ? atomicAdd(&cursor[t], lh[t]) : 0;   // reserve range
    __syncthreads();
#pragma unroll
    for (int i = 0; i < 4; ++i)
        if (r[i] >= 0) eidx[lbase[r[i]] + lr[i]] = blockIdx.x * 1024 + i * 256 + t;
}

// ---------------- batched scoring v3 (restored): contiguous chunk range per block ----------------
// R7 lesson: v4's per-thread zt registers read each z-row 8x redundantly (8 threads per 16B
// segment) and VGPR 88 cut occupancy — 66us vs v3's <=45us. v3: cooperative LDS staging of
// zh+zt (1 float4/thread), W[r] cached across same-relation chunks (re-stage ~3% of steps).
__global__ __launch_bounds__(256) void k_score_r(const float* __restrict__ z, const float* __restrict__ relW,
                                                 const int* __restrict__ eidx, const int* __restrict__ head,
                                                 const int* __restrict__ tail, const int* __restrict__ roff,
                                                 const int* __restrict__ chunkoff, float* __restrict__ out,
                                                 int R_, int cpb) {
    __shared__ __align__(16) float Wl[TD * TD];      // 64 KB
    __shared__ __align__(16) float zhL[SC_T * TD];   // 4 KB
    __shared__ __align__(16) float ztL[SC_T * TD];   // 4 KB
    __shared__ int eids[SC_T];
    __shared__ int co[17], ro[17];
    __shared__ float red[4][SC_T];
    const int t = threadIdx.x;
    if (t < 17 && t <= R_) { co[t] = chunkoff[t]; ro[t] = roff[t]; }
    __syncthreads();
    const int nch = co[R_];                    // total real chunks
    int b = blockIdx.x * cpb;
    const int bend = min(nch, b + cpb);
    int r = 0, rprev = -1;
    for (; b < bend; ++b) {
        while (co[r + 1] <= b) ++r;            // monotone in b; uniform across block
        const int base = ro[r] + (b - co[r]) * SC_T;
        const int nt = min(SC_T, ro[r + 1] - base);
        if (t < SC_T) eids[t] = (t < nt) ? eidx[base + t] : -1;
        const bool newW = (r != rprev);
        rprev = r;
        __syncthreads();                       // eids visible; zhL free (post-compute barrier)
        {   // stage zh/zt: 256 float4, 1 per thread
            int tt = t >> 5, c4 = t & 31;
            float4 vh = make_float4(0.f, 0.f, 0.f, 0.f), vt = vh;
            int e = eids[tt];
            if (e >= 0) {
                vh = ((const float4*)(z + (size_t)head[e] * TD))[c4];
                vt = ((const float4*)(z + (size_t)tail[e] * TD))[c4];
            }
            ((float4*)(zhL + tt * TD))[c4] = vh;
            ((float4*)(ztL + tt * TD))[c4] = vt;
        }
        if (newW) {   // stage W[r]: 4096 float4 (only on relation change)
            const float4* W4 = (const float4*)(relW + (size_t)r * TD * TD);
            float4* Wl4 = (float4*)Wl;
#pragma unroll
            for (int i = 0; i < 16; ++i) Wl4[t + i * 256] = W4[t + i * 256];
        }
        __syncthreads();

        const int c  = (t & 31) * 4;    // cols c..c+3
        const int i0 = (t >> 5) * 16;   // 16-row i segment
        float4 acc[SC_T];
#pragma unroll
        for (int u = 0; u < SC_T; ++u) acc[u] = make_float4(0.f, 0.f, 0.f, 0.f);
#pragma unroll 4
        for (int i = i0; i < i0 + 16; ++i) {
            float4 wv = *(const float4*)&Wl[i * TD + c];
#pragma unroll
            for (int u = 0; u < SC_T; ++u) {
                float h = zhL[u * TD + i];
                acc[u].x = fmaf(h, wv.x, acc[u].x);
                acc[u].y = fmaf(h, wv.y, acc[u].y);
                acc[u].z = fmaf(h, wv.z, acc[u].z);
                acc[u].w = fmaf(h, wv.w, acc[u].w);
            }
        }
        float pth[SC_T];
#pragma unroll
        for (int u = 0; u < SC_T; ++u) {
            float4 z4 = *(const float4*)&ztL[u * TD + c];
            pth[u] = acc[u].x * z4.x + acc[u].y * z4.y + acc[u].z * z4.z + acc[u].w * z4.w;
        }
#pragma unroll
        for (int off = 32; off > 0; off >>= 1)
#pragma unroll
            for (int u = 0; u < SC_T; ++u) pth[u] += __shfl_down(pth[u], off);
        if ((t & 63) == 0) {
            int wv = t >> 6;
#pragma unroll
            for (int u = 0; u < SC_T; ++u) red[wv][u] = pth[u];
        }
        __syncthreads();
        if (t < SC_T) {
            int e = eids[t];
            if (e >= 0) out[e] = red[0][t] + red[1][t] + red[2][t] + red[3][t];
        }
    }
}

extern "C" void kernel_launch(void* const* d_in, const int* in_sizes, int n_in,
                              void* d_out, int out_size, void* d_ws, size_t ws_size,
                              hipStream_t stream) {
    const float* x0   = (const float*)d_in[0];
    const float* W1   = (const float*)d_in[1];
    const float* b1   = (const float*)d_in[2];
    const float* W2   = (const float*)d_in[3];
    const float* b2   = (const float*)d_in[4];
    const float* relW = (const float*)d_in[5];
    const int*   ei   = (const int*)d_in[6];
    const int*   rel  = (const int*)d_in[7];
    const int*   head = (const int*)d_in[8];
    const int*   tail = (const int*)d_in[9];
    float* outp = (float*)d_out;

    const int N_  = in_sizes[0] / TD;
    const int E_  = in_sizes[6] / 2;
    const int ES_ = in_sizes[7];
    const int R_  = in_sizes[5] / (TD * TD);
    const int ntiles64 = (N_ + 63) / 64;
    const int NB    = (N_ + (1 << BKT_SH) - 1) >> BKT_SH;   // <= 1024 for N <= 131072
    const int chunk  = (E_ + NBLK - 1) / NBLK;
    const int rchunk = (ES_ + NBLK - 1) / NBLK;
    const int maxch  = (ES_ + SC_T - 1) / SC_T + R_;        // upper bound on chunk count
    const int sgrid  = maxch < 512 ? maxch : 512;           // 2 blocks/CU
    const int cpb    = (maxch + sgrid - 1) / sgrid;         // chunks per block (contiguous)

    char* p = (char*)d_ws;
    auto alloc = [&](size_t bytes) { char* r = p; p += (bytes + 255) & ~(size_t)255; return r; };
    float*          dinv   = (float*)         alloc((size_t)N_ * 4);
    int*            rowptr = (int*)           alloc(((size_t)N_ + 1) * 4);
    int*            bh     = (int*)           alloc((size_t)NB * NBLK * 4);
    int*            tot    = (int*)           alloc((size_t)NB * 4);
    int*            boff   = (int*)           alloc(((size_t)NB + 1) * 4);
    int*            esrc   = (int*)           alloc((size_t)E_ * 4);
    unsigned short* Wt     = (unsigned short*)alloc((size_t)2 * 16384 * 2);   // W1h^T, W2h^T
    int*            rcount = (int*)           alloc((size_t)R_ * 4);
    int*            roff   = (int*)           alloc(((size_t)R_ + 1) * 4);
    int*            chkoff = (int*)           alloc(((size_t)R_ + 1) * 4);
    int*            cursor = (int*)           alloc((size_t)R_ * 4);
    int*            eidx   = (int*)           alloc((size_t)ES_ * 4);
    unsigned char*  bufA   = (unsigned char*) alloc((size_t)N_ * TD);         // int8 messages
    float*          sc     = (float*)         alloc((size_t)N_ * 4);          // per-row scales
    float*          bufB   = (float*)         alloc((size_t)N_ * TD * 4);     // f32 conv out
    int*            ebuf   = (int*)bufA;   // alias: dead before first k_gemm writes bufA (E*4 <= N*TD)

    hipMemsetAsync(rcount, 0, (size_t)R_ * 4, stream);

    // atomic-free CSR: hist(+rel histo, +wsplit) -> scanA -> scanB(+roff) -> scatter -> build
    kc_hist <<<NBLK + 64, 256, 0, stream>>>(ei, bh, rel, rcount, W1, W2, Wt, E_, ES_, NB, chunk, rchunk);
    kc_scanA<<<NB, 64, 0, stream>>>(bh, tot, NB);
    kc_scanB<<<1, 256, 0, stream>>>(tot, boff, NB, rowptr + N_, rcount, roff, chkoff, cursor, R_);
    kc_scat <<<NBLK, 256, 0, stream>>>(ei, bh, boff, ebuf, E_, NB, chunk);
    kc_build<<<NB, 256, 0, stream>>>(ebuf, boff, rowptr, dinv, esrc, N_);

    k_bucket<<<(ES_ + 1023) / 1024, 256, 0, stream>>>(rel, cursor, eidx, ES_);

    // conv1: bufA,sc = int8(dinv * (x0 @ W1)); bufB = relu(dinv*agg(bufA*sc) + b1)
    k_gemm<<<ntiles64, 256, 0, stream>>>(x0, Wt, dinv, bufA, sc, N_);
    k_agg <<<(N_ + 15) / 16, 256, 0, stream>>>(bufA, sc, rowptr, esrc, dinv, b1, bufB, N_, 1);
    // conv2: bufA,sc = int8(dinv * (bufB @ W2)); bufB = dinv*agg(bufA*sc) + b2  (= z)
    k_gemm<<<ntiles64, 256, 0, stream>>>(bufB, Wt + 16384, dinv, bufA, sc, N_);
    k_agg <<<(N_ + 15) / 16, 256, 0, stream>>>(bufA, sc, rowptr, esrc, dinv, b2, bufB, N_, 0);

    // scoring: contiguous chunk ranges, W cached across same-relation chunks
    k_score_r<<<sgrid, 256, 0, stream>>>(bufB, relW, eidx, head, tail,
                                         roff, chkoff, outp, R_, cpb);
}

// Round 9
// 301.082 us; speedup vs baseline: 1.0981x; 1.0140x over previous
//
#include <hip/hip_runtime.h>
#include <hip/hip_bf16.h>

#define TD 128    // feature dim, fixed by problem
#define WS 136    // padded W-LDS row stride in bf16 (272 B: 16B-aligned, bank-uniform for b128)
#define SC_T 8    // triples per scoring block (R4 lesson: LDS > 80KB -> 1 block/CU cliff)
#define BKT_SH 7  // 128 nodes per CSR bucket (NB = ceil(N/128) <= 1024 for N <= 131072)
#define NBLK 256  // partition blocks for hist/scat passes

typedef __attribute__((ext_vector_type(8))) short bf16x8;   // 8 bf16 = 4 VGPR (MFMA A/B frag)
typedef __attribute__((ext_vector_type(4))) float f32x4;    // MFMA C/D frag

static __device__ __forceinline__ unsigned short f2bf(float f) {
    unsigned int u = __float_as_uint(f);
    u += 0x7fffu + ((u >> 16) & 1u);   // round-to-nearest-even
    return (unsigned short)(u >> 16);
}
static __device__ __forceinline__ float bf2f(unsigned short h) {
    return __uint_as_float((unsigned int)h << 16);
}

// ================= atomic-free CSR build =================
// R3: global atomic RMWs hit a ~24 op/ns chip floor with ~32B/op HBM write-through; replaced
// by LDS-histogram multi-split (zero global atomics). R7: wsplit fused in as extra blocks.

// pass 1: per-block bucket histogram (+ relation histogram) + fused W transpose/bf16 split.
__global__ __launch_bounds__(256) void kc_hist(const int* __restrict__ ei, int* __restrict__ bh,
                                               const int* __restrict__ rel, int* __restrict__ rcount,
                                               const float* __restrict__ W1, const float* __restrict__ W2,
                                               unsigned short* __restrict__ Wt,
                                               int E_, int ES_, int NB, int chunk, int rchunk) {
    __shared__ int lh[1024];
    __shared__ int rh[16];
    int t = threadIdx.x, blk = blockIdx.x;
    if (blk >= NBLK) {   // fused wsplit: blocks NBLK..NBLK+63, bf16-hi only (R7: lo planes dropped)
        int idx = (blk - NBLK) * 256 + t;   // 0..16383 = k*128+n (coalesced read)
        int k = idx >> 7, n = idx & 127;
        Wt[n * 128 + k] = f2bf(W1[idx]);
        Wt[16384 + n * 128 + k] = f2bf(W2[idx]);
        return;
    }
    for (int j = t; j < NB; j += 256) lh[j] = 0;
    if (t < 16) rh[t] = 0;
    __syncthreads();
    int e0 = blk * chunk, e1 = min(E_, e0 + chunk);
    for (int e = e0 + t; e < e1; e += 256)
        atomicAdd(&lh[ei[E_ + e] >> BKT_SH], 1);   // LDS atomic
    int r0 = blk * rchunk, r1 = min(ES_, r0 + rchunk);
    for (int e = r0 + t; e < r1; e += 256)
        atomicAdd(&rh[rel[e]], 1);                 // LDS atomic
    __syncthreads();
    for (int j = t; j < NB; j += 256) bh[(size_t)j * NBLK + blk] = lh[j];
    if (t < 16 && rh[t]) atomicAdd(&rcount[t], rh[t]);   // fire-and-forget, 16/block
}

// pass 2a: per bucket, exclusive scan over the NBLK block counts (in place); tot[b] = bucket size
__global__ __launch_bounds__(64) void kc_scanA(int* __restrict__ bh, int* __restrict__ tot, int NB) {
    int b = blockIdx.x, l = threadIdx.x;
    int* row = bh + (size_t)b * NBLK;
    int run = 0;
#pragma unroll
    for (int g = 0; g < NBLK / 64; ++g) {
        int v = row[g * 64 + l];
        int x = v;
#pragma unroll
        for (int off = 1; off < 64; off <<= 1) {
            int y = __shfl_up(x, off);
            if (l >= off) x += y;
        }
        row[g * 64 + l] = run + x - v;   // exclusive within bucket
        run += __shfl(x, 63);
    }
    if (l == 0) tot[b] = run;
}

// pass 2b: single-block exclusive scan of bucket totals -> boff[0..NB], rowptr[N] = E.
// R7: relation-offset scan + cursor init folded in (rcount final since kc_hist).
__global__ __launch_bounds__(256) void kc_scanB(const int* __restrict__ tot, int* __restrict__ boff,
                                                int NB, int* __restrict__ rowptrN,
                                                const int* __restrict__ rcount, int* __restrict__ roff,
                                                int* __restrict__ chunkoff, int* __restrict__ cursor, int nr) {
    __shared__ int wsum[4];
    int t = threadIdx.x;
    int base = t * 4;
    int a0 = (base     < NB) ? tot[base]     : 0;
    int a1 = (base + 1 < NB) ? tot[base + 1] : 0;
    int a2 = (base + 2 < NB) ? tot[base + 2] : 0;
    int a3 = (base + 3 < NB) ? tot[base + 3] : 0;
    int s1 = a0 + a1, s2 = s1 + a2, tt = s2 + a3;
    int lane = t & 63, wv = t >> 6;
    int x = tt;
#pragma unroll
    for (int off = 1; off < 64; off <<= 1) {
        int y = __shfl_up(x, off);
        if (lane >= off) x += y;
    }
    if (lane == 63) wsum[wv] = x;
    __syncthreads();
    int woff = 0;
    for (int w = 0; w < wv; ++w) woff += wsum[w];
    int excl = woff + x - tt;
    if (base     < NB) boff[base]     = excl;
    if (base + 1 < NB) boff[base + 1] = excl + a0;
    if (base + 2 < NB) boff[base + 2] = excl + s1;
    if (base + 3 < NB) boff[base + 3] = excl + s2;
    if (t == 255) { boff[NB] = woff + x; *rowptrN = woff + x; }
    if (t == 0) {   // relation offsets (serial, nr <= 16)
        int run = 0, crun = 0;
        for (int r = 0; r < nr; ++r) {
            roff[r] = run; chunkoff[r] = crun; cursor[r] = run;
            run += rcount[r]; crun += (rcount[r] + SC_T - 1) / SC_T;
        }
        roff[nr] = run; chunkoff[nr] = crun;
    }
}

// pass 3: scatter edges into bucket-grouped ebuf, packed (src<<7)|(dst&127). LDS-atomic ranks.
__global__ __launch_bounds__(256) void kc_scat(const int* __restrict__ ei, const int* __restrict__ bh,
                                               const int* __restrict__ boff, int* __restrict__ ebuf,
                                               int E_, int NB, int chunk) {
    __shared__ int lh[1024];
    int t = threadIdx.x, blk = blockIdx.x;
    for (int j = t; j < NB; j += 256) lh[j] = 0;
    __syncthreads();
    int e0 = blk * chunk, e1 = min(E_, e0 + chunk);
    for (int e = e0 + t; e < e1; e += 256) {
        int s = ei[e];
        int d = ei[E_ + e];
        int b = d >> BKT_SH;
        int lr = atomicAdd(&lh[b], 1);   // LDS atomic: rank within (block, bucket)
        int slot = boff[b] + bh[(size_t)b * NBLK + blk] + lr;
        ebuf[slot] = (s << BKT_SH) | (d & ((1 << BKT_SH) - 1));
    }
}

// pass 4: one block per bucket -> exact per-node counting sort. Writes rowptr, dinv, esrc.
__global__ __launch_bounds__(256) void kc_build(const int* __restrict__ ebuf, const int* __restrict__ boff,
                                                int* __restrict__ rowptr, float* __restrict__ dinv,
                                                int* __restrict__ esrc, int n) {
    __shared__ int hist[128], excl[128], cur[128];
    __shared__ int w0;
    int b = blockIdx.x, t = threadIdx.x;
    int node0 = b << BKT_SH;
    int s = boff[b], e = boff[b + 1];
    if (t < 128) { hist[t] = 0; cur[t] = 0; }
    __syncthreads();
    for (int i = s + t; i < e; i += 256)
        atomicAdd(&hist[ebuf[i] & 127], 1);   // LDS atomic
    __syncthreads();
    // scan the 128 counts (waves 0,1 active; uniform syncs)
    int v = (t < 128) ? hist[t] : 0;
    int lane = t & 63, wv = t >> 6;
    int x = v;
#pragma unroll
    for (int off = 1; off < 64; off <<= 1) {
        int y = __shfl_up(x, off);
        if (lane >= off) x += y;
    }
    if (t == 63) w0 = x;
    __syncthreads();
    if (t < 128) {
        int ex = x - v + (wv == 1 ? w0 : 0);
        excl[t] = ex;
        int node = node0 + t;
        if (node < n) {
            rowptr[node] = s + ex;
            dinv[node] = (v > 0) ? 1.0f / sqrtf((float)v) : 0.0f;
        }
    }
    __syncthreads();
    for (int i = s + t; i < e; i += 256) {
        int p = ebuf[i];
        int loc = p & 127;
        int lr = atomicAdd(&cur[loc], 1);   // LDS atomic
        esrc[s + excl[loc] + lr] = p >> BKT_SH;
    }
}

// ---------------- MFMA GEMM v9: bf16-only, 34KB LDS, optional bf16 A-input ----------------
// R7: hi/lo split dropped (int8 output quant dominates). R9: ibf16 path reads the A tile as
// bf16 directly (conv2's input bufB is now written bf16 by k_agg — bit-identical to the old
// f32-write+f2bf-convert, half the bytes, zero convert ALU).
__global__ __launch_bounds__(256, 4) void k_gemm(const void* __restrict__ Xv,
                                                 const unsigned short* __restrict__ Wth,
                                                 const float* __restrict__ scale,
                                                 unsigned char* __restrict__ out8,
                                                 float* __restrict__ scOut,
                                                 int nrows, int ibf16) {
    __shared__ __align__(16) unsigned short Wl[128 * WS];   // 34 KB; reused by epilogue transpose
    const int t = threadIdx.x;
    const int w = t >> 6;
    const int lane = t & 63;
    const int l15 = lane & 15;
    const int quad = lane >> 4;
    const int rbase = blockIdx.x * 64 + w * 16;   // wave's 16-row tile
    const int arow = rbase + l15;                 // this lane's A row
    const bool avalid = arow < nrows;

    // A fragments: bf16 direct loads (16B/kc) or f32 loads + convert (32B/kc)
    bf16x8 ah[4];
    const bf16x8 zero8 = {0, 0, 0, 0, 0, 0, 0, 0};
    if (ibf16) {
        const unsigned short* Xb = (const unsigned short*)Xv;
#pragma unroll
        for (int kc = 0; kc < 4; ++kc)
            ah[kc] = avalid ? *(const bf16x8*)(Xb + (size_t)arow * TD + kc * 32 + quad * 8) : zero8;
    } else {
        const float* X = (const float*)Xv;
        float4 xa[4][2];
#pragma unroll
        for (int kc = 0; kc < 4; ++kc) {
            const float* src = X + (size_t)arow * TD + kc * 32 + quad * 8;
            xa[kc][0] = avalid ? *(const float4*)src       : make_float4(0.f, 0.f, 0.f, 0.f);
            xa[kc][1] = avalid ? *(const float4*)(src + 4) : make_float4(0.f, 0.f, 0.f, 0.f);
        }
#pragma unroll
        for (int kc = 0; kc < 4; ++kc)
#pragma unroll
            for (int j = 0; j < 8; ++j) {
                float v = (j < 4) ? ((const float*)&xa[kc][0])[j] : ((const float*)&xa[kc][1])[j - 4];
                ah[kc][j] = (short)f2bf(v);
            }
    }

    // stage W-hi -> padded LDS: 2048 uint4, 8 per thread
    {
        const uint4* gh = (const uint4*)Wth;
#pragma unroll
        for (int it = 0; it < 8; ++it) {
            int idx = t + it * 256;            // 0..2047
            int n = idx >> 4, kg = idx & 15;   // row n, k-group kg (8 bf16 each)
            uint4 vh = gh[idx];
            *(uint4*)&Wl[n * WS + kg * 8] = vh;
        }
    }
    __syncthreads();

    f32x4 acc[8];
#pragma unroll
    for (int b = 0; b < 8; ++b) acc[b] = (f32x4){0.f, 0.f, 0.f, 0.f};

#pragma unroll
    for (int kc = 0; kc < 4; ++kc) {
        const int koff = kc * 32 + quad * 8;
#pragma unroll
        for (int b = 0; b < 8; ++b) {
            bf16x8 bh = *(const bf16x8*)&Wl[(b * 16 + l15) * WS + koff];
            acc[b] = __builtin_amdgcn_mfma_f32_16x16x32_bf16(ah[kc], bh, acc[b], 0, 0, 0);
        }
    }

    __syncthreads();   // all waves done reading Wl -> safe to reuse as transpose buffer

    // epilogue: m = acc*dinv; rowmax over 16 lanes; int8 quantize; LDS byte transpose
    {
        unsigned char* lds8 = (unsigned char*)&Wl[0];
        const int grow = rbase + quad * 4;        // multiple of 4; nrows % 4 == 0
        float4 s4 = make_float4(0.f, 0.f, 0.f, 0.f);
        if (grow < nrows) s4 = *(const float4*)&scale[grow];
        float rm[4];
#pragma unroll
        for (int j = 0; j < 4; ++j) {
            float sj = ((const float*)&s4)[j];
            float mx = 0.f;
#pragma unroll
            for (int b = 0; b < 8; ++b) {
                acc[b][j] *= sj;
                mx = fmaxf(mx, fabsf(acc[b][j]));
            }
            rm[j] = mx;
        }
#pragma unroll
        for (int m_ = 1; m_ < 16; m_ <<= 1)
#pragma unroll
            for (int j = 0; j < 4; ++j) rm[j] = fmaxf(rm[j], __shfl_xor(rm[j], m_));
        float inv[4];
#pragma unroll
        for (int j = 0; j < 4; ++j) inv[j] = rm[j] > 0.f ? 127.f / rm[j] : 0.f;
#pragma unroll
        for (int j = 0; j < 4; ++j) {
            int lrow = w * 16 + quad * 4 + j;
#pragma unroll
            for (int b = 0; b < 8; ++b) {
                int q = (int)rintf(acc[b][j] * inv[j]);
                lds8[lrow * 128 + b * 16 + l15] = (unsigned char)(signed char)q;
            }
        }
        if (l15 == 0 && grow < nrows)
            *(float4*)&scOut[grow] = make_float4(rm[0] * (1.f / 127.f), rm[1] * (1.f / 127.f),
                                                 rm[2] * (1.f / 127.f), rm[3] * (1.f / 127.f));
    }
    __syncthreads();
    {   // linear coalesced copy: 2048 dwords (64 rows x 128 B)
        const unsigned int* lds32 = (const unsigned int*)&Wl[0];
        unsigned int* g32 = (unsigned int*)out8;
#pragma unroll
        for (int k = 0; k < 8; ++k) {
            int idx = t + k * 256;
            int row = blockIdx.x * 64 + (idx >> 5);
            if (row < nrows) g32[(size_t)blockIdx.x * 2048 + idx] = lds32[idx];
        }
    }
}

// ---------------- CSR aggregation v3: int8 gather, f32 accumulate, bf16-or-f32 output ----------------
// R6: FETCH 86MB ~= the 12.8MB x 8-XCD compulsory bound (gather at floor). R9: conv1's output
// is consumed only by gemm2's f2bf convert -> writing bf16 here is BIT-IDENTICAL downstream
// and halves WRITE 50->25MB. conv2's z output stays f32 (scoring consumes it at full precision).
#define ACCI8(p, u, s) \
    p##0 = fmaf(s, (float)(signed char)(u.x      ), p##0); \
    p##1 = fmaf(s, (float)(signed char)(u.x >>  8), p##1); \
    p##2 = fmaf(s, (float)(signed char)(u.x >> 16), p##2); \
    p##3 = fmaf(s, (float)(signed char)(u.x >> 24), p##3); \
    p##4 = fmaf(s, (float)(signed char)(u.y      ), p##4); \
    p##5 = fmaf(s, (float)(signed char)(u.y >>  8), p##5); \
    p##6 = fmaf(s, (float)(signed char)(u.y >> 16), p##6); \
    p##7 = fmaf(s, (float)(signed char)(u.y >> 24), p##7);

__global__ __launch_bounds__(256) void k_agg(const unsigned char* __restrict__ hs8, const float* __restrict__ sc,
                                             const int* __restrict__ rowptr, const int* __restrict__ esrc,
                                             const float* __restrict__ dinv, const float* __restrict__ bias,
                                             void* __restrict__ outv, int n, int relu, int obf16) {
    int node = blockIdx.x * 16 + (threadIdx.x >> 4);
    int lane = threadIdx.x & 15;
    if (node >= n) return;
    int s = rowptr[node], e = rowptr[node + 1];
    const uint2* h8 = (const uint2*)hs8;   // 16 lanes x 8B = one 128B int8 row
    float a0 = 0.f, a1 = 0.f, a2 = 0.f, a3 = 0.f, a4 = 0.f, a5 = 0.f, a6 = 0.f, a7 = 0.f;
    float c0 = 0.f, c1 = 0.f, c2 = 0.f, c3 = 0.f, c4 = 0.f, c5 = 0.f, c6 = 0.f, c7 = 0.f;
    int i = s;
    for (; i + 4 <= e; i += 4) {
        int s0 = esrc[i], s1 = esrc[i + 1], s2 = esrc[i + 2], s3 = esrc[i + 3];
        uint2 u0 = h8[(size_t)s0 * 16 + lane];
        uint2 u1 = h8[(size_t)s1 * 16 + lane];
        uint2 u2 = h8[(size_t)s2 * 16 + lane];
        uint2 u3 = h8[(size_t)s3 * 16 + lane];
        float f0 = sc[s0], f1 = sc[s1], f2 = sc[s2], f3 = sc[s3];
        ACCI8(a, u0, f0)
        ACCI8(c, u1, f1)
        ACCI8(a, u2, f2)
        ACCI8(c, u3, f3)
    }
    for (; i < e; ++i) {
        int s0 = esrc[i];
        uint2 u = h8[(size_t)s0 * 16 + lane];
        float f = sc[s0];
        ACCI8(a, u, f)
    }
    a0 += c0; a1 += c1; a2 += c2; a3 += c3;
    a4 += c4; a5 += c5; a6 += c6; a7 += c7;
    float di = dinv[node];
    float4 b0 = ((const float4*)bias)[lane * 2];
    float4 b1 = ((const float4*)bias)[lane * 2 + 1];
    float o0 = fmaf(di, a0, b0.x);
    float o1 = fmaf(di, a1, b0.y);
    float o2 = fmaf(di, a2, b0.z);
    float o3 = fmaf(di, a3, b0.w);
    float o4 = fmaf(di, a4, b1.x);
    float o5 = fmaf(di, a5, b1.y);
    float o6 = fmaf(di, a6, b1.z);
    float o7 = fmaf(di, a7, b1.w);
    if (relu) {
        o0 = fmaxf(o0, 0.f); o1 = fmaxf(o1, 0.f); o2 = fmaxf(o2, 0.f); o3 = fmaxf(o3, 0.f);
        o4 = fmaxf(o4, 0.f); o5 = fmaxf(o5, 0.f); o6 = fmaxf(o6, 0.f); o7 = fmaxf(o7, 0.f);
    }
    if (obf16) {
        unsigned int p0 = (unsigned int)f2bf(o0) | ((unsigned int)f2bf(o1) << 16);
        unsigned int p1 = (unsigned int)f2bf(o2) | ((unsigned int)f2bf(o3) << 16);
        unsigned int p2 = (unsigned int)f2bf(o4) | ((unsigned int)f2bf(o5) << 16);
        unsigned int p3 = (unsigned int)f2bf(o6) | ((unsigned int)f2bf(o7) << 16);
        ((uint4*)outv)[(size_t)node * 16 + lane] = make_uint4(p0, p1, p2, p3);
    } else {
        ((float4*)outv)[(size_t)node * 32 + lane * 2]     = make_float4(o0, o1, o2, o3);
        ((float4*)outv)[(size_t)node * 32 + lane * 2 + 1] = make_float4(o4, o5, o6, o7);
    }
}

__global__ __launch_bounds__(256) void k_bucket(const int* __restrict__ rel, int* __restrict__ cursor,
                                                int* __restrict__ eidx, int es) {
    __shared__ int lh[16];
    __shared__ int lbase[16];
    int t = threadIdx.x;
    if (t < 16) lh[t] = 0;
    __syncthreads();
    int r[4], lr[4];
#pragma unroll
    for (int i = 0; i < 4; ++i) {
        int e = blockIdx.x * 1024 + i * 256 + t;
        if (e < es) {
            r[i] = rel[e];
            lr[i] = atomicAdd(&lh[r[i]], 1);   // LDS atomic: intra-block rank
        } else r[i] = -1;
    }
    __syncthreads();
    if (t < 16) lbase[t] = lh[t] ? atomicAdd(&cursor[t], lh[t]) : 0;   // reserve range
    __syncthreads();
#pragma unroll
    for (int i = 0; i < 4; ++i)
        if (r[i] >= 0) eidx[lbase[r[i]] + lr[i]] = blockIdx.x * 1024 + i * 256 + t;
}

// ---------------- batched scoring v3: contiguous chunk range per block ----------------
// R7 lesson: cooperative LDS staging of zh+zt (1 float4/thread) beats per-thread registers
// (8x redundant reads + VGPR-occupancy loss). W[r] cached across same-relation chunks.
__global__ __launch_bounds__(256) void k_score_r(const float* __restrict__ z, const float* __restrict__ relW,
                                                 const int* __restrict__ eidx, const int* __restrict__ head,
                                                 const int* __restrict__ tail, const int* __restrict__ roff,
                                                 const int* __restrict__ chunkoff, float* __restrict__ out,
                                                 int R_, int cpb) {
    __shared__ __align__(16) float Wl[TD * TD];      // 64 KB
    __shared__ __align__(16) float zhL[SC_T * TD];   // 4 KB
    __shared__ __align__(16) float ztL[SC_T * TD];   // 4 KB
    __shared__ int eids[SC_T];
    __shared__ int co[17], ro[17];
    __shared__ float red[4][SC_T];
    const int t = threadIdx.x;
    if (t < 17 && t <= R_) { co[t] = chunkoff[t]; ro[t] = roff[t]; }
    __syncthreads();
    const int nch = co[R_];                    // total real chunks
    int b = blockIdx.x * cpb;
    const int bend = min(nch, b + cpb);
    int r = 0, rprev = -1;
    for (; b < bend; ++b) {
        while (co[r + 1] <= b) ++r;            // monotone in b; uniform across block
        const int base = ro[r] + (b - co[r]) * SC_T;
        const int nt = min(SC_T, ro[r + 1] - base);
        if (t < SC_T) eids[t] = (t < nt) ? eidx[base + t] : -1;
        const bool newW = (r != rprev);
        rprev = r;
        __syncthreads();                       // eids visible; zhL free (post-compute barrier)
        {   // stage zh/zt: 256 float4, 1 per thread
            int tt = t >> 5, c4 = t & 31;
            float4 vh = make_float4(0.f, 0.f, 0.f, 0.f), vt = vh;
            int e = eids[tt];
            if (e >= 0) {
                vh = ((const float4*)(z + (size_t)head[e] * TD))[c4];
                vt = ((const float4*)(z + (size_t)tail[e] * TD))[c4];
            }
            ((float4*)(zhL + tt * TD))[c4] = vh;
            ((float4*)(ztL + tt * TD))[c4] = vt;
        }
        if (newW) {   // stage W[r]: 4096 float4 (only on relation change)
            const float4* W4 = (const float4*)(relW + (size_t)r * TD * TD);
            float4* Wl4 = (float4*)Wl;
#pragma unroll
            for (int i = 0; i < 16; ++i) Wl4[t + i * 256] = W4[t + i * 256];
        }
        __syncthreads();

        const int c  = (t & 31) * 4;    // cols c..c+3
        const int i0 = (t >> 5) * 16;   // 16-row i segment
        float4 acc[SC_T];
#pragma unroll
        for (int u = 0; u < SC_T; ++u) acc[u] = make_float4(0.f, 0.f, 0.f, 0.f);
#pragma unroll 4
        for (int i = i0; i < i0 + 16; ++i) {
            float4 wv = *(const float4*)&Wl[i * TD + c];
#pragma unroll
            for (int u = 0; u < SC_T; ++u) {
                float h = zhL[u * TD + i];
                acc[u].x = fmaf(h, wv.x, acc[u].x);
                acc[u].y = fmaf(h, wv.y, acc[u].y);
                acc[u].z = fmaf(h, wv.z, acc[u].z);
                acc[u].w = fmaf(h, wv.w, acc[u].w);
            }
        }
        float pth[SC_T];
#pragma unroll
        for (int u = 0; u < SC_T; ++u) {
            float4 z4 = *(const float4*)&ztL[u * TD + c];
            pth[u] = acc[u].x * z4.x + acc[u].y * z4.y + acc[u].z * z4.z + acc[u].w * z4.w;
        }
#pragma unroll
        for (int off = 32; off > 0; off >>= 1)
#pragma unroll
            for (int u = 0; u < SC_T; ++u) pth[u] += __shfl_down(pth[u], off);
        if ((t & 63) == 0) {
            int wv = t >> 6;
#pragma unroll
            for (int u = 0; u < SC_T; ++u) red[wv][u] = pth[u];
        }
        __syncthreads();
        if (t < SC_T) {
            int e = eids[t];
            if (e >= 0) out[e] = red[0][t] + red[1][t] + red[2][t] + red[3][t];
        }
    }
}

extern "C" void kernel_launch(void* const* d_in, const int* in_sizes, int n_in,
                              void* d_out, int out_size, void* d_ws, size_t ws_size,
                              hipStream_t stream) {
    const float* x0   = (const float*)d_in[0];
    const float* W1   = (const float*)d_in[1];
    const float* b1   = (const float*)d_in[2];
    const float* W2   = (const float*)d_in[3];
    const float* b2   = (const float*)d_in[4];
    const float* relW = (const float*)d_in[5];
    const int*   ei   = (const int*)d_in[6];
    const int*   rel  = (const int*)d_in[7];
    const int*   head = (const int*)d_in[8];
    const int*   tail = (const int*)d_in[9];
    float* outp = (float*)d_out;

    const int N_  = in_sizes[0] / TD;
    const int E_  = in_sizes[6] / 2;
    const int ES_ = in_sizes[7];
    const int R_  = in_sizes[5] / (TD * TD);
    const int ntiles64 = (N_ + 63) / 64;
    const int NB    = (N_ + (1 << BKT_SH) - 1) >> BKT_SH;   // <= 1024 for N <= 131072
    const int chunk  = (E_ + NBLK - 1) / NBLK;
    const int rchunk = (ES_ + NBLK - 1) / NBLK;
    const int maxch  = (ES_ + SC_T - 1) / SC_T + R_;        // upper bound on chunk count
    const int sgrid  = maxch < 512 ? maxch : 512;           // 2 blocks/CU
    const int cpb    = (maxch + sgrid - 1) / sgrid;         // chunks per block (contiguous)

    char* p = (char*)d_ws;
    auto alloc = [&](size_t bytes) { char* r = p; p += (bytes + 255) & ~(size_t)255; return r; };
    float*          dinv   = (float*)         alloc((size_t)N_ * 4);
    int*            rowptr = (int*)           alloc(((size_t)N_ + 1) * 4);
    int*            bh     = (int*)           alloc((size_t)NB * NBLK * 4);
    int*            tot    = (int*)           alloc((size_t)NB * 4);
    int*            boff   = (int*)           alloc(((size_t)NB + 1) * 4);
    int*            esrc   = (int*)           alloc((size_t)E_ * 4);
    unsigned short* Wt     = (unsigned short*)alloc((size_t)2 * 16384 * 2);   // W1h^T, W2h^T
    int*            rcount = (int*)           alloc((size_t)R_ * 4);
    int*            roff   = (int*)           alloc(((size_t)R_ + 1) * 4);
    int*            chkoff = (int*)           alloc(((size_t)R_ + 1) * 4);
    int*            cursor = (int*)           alloc((size_t)R_ * 4);
    int*            eidx   = (int*)           alloc((size_t)ES_ * 4);
    unsigned char*  bufA   = (unsigned char*) alloc((size_t)N_ * TD);         // int8 messages
    float*          sc     = (float*)         alloc((size_t)N_ * 4);          // per-row scales
    float*          bufB   = (float*)         alloc((size_t)N_ * TD * 4);     // conv out (bf16 or f32)
    int*            ebuf   = (int*)bufA;   // alias: dead before first k_gemm writes bufA (E*4 <= N*TD)

    hipMemsetAsync(rcount, 0, (size_t)R_ * 4, stream);

    // atomic-free CSR: hist(+rel histo, +wsplit) -> scanA -> scanB(+roff) -> scatter -> build
    kc_hist <<<NBLK + 64, 256, 0, stream>>>(ei, bh, rel, rcount, W1, W2, Wt, E_, ES_, NB, chunk, rchunk);
    kc_scanA<<<NB, 64, 0, stream>>>(bh, tot, NB);
    kc_scanB<<<1, 256, 0, stream>>>(tot, boff, NB, rowptr + N_, rcount, roff, chkoff, cursor, R_);
    kc_scat <<<NBLK, 256, 0, stream>>>(ei, bh, boff, ebuf, E_, NB, chunk);
    kc_build<<<NB, 256, 0, stream>>>(ebuf, boff, rowptr, dinv, esrc, N_);

    k_bucket<<<(ES_ + 1023) / 1024, 256, 0, stream>>>(rel, cursor, eidx, ES_);

    // conv1: bufA,sc = int8(dinv * (x0 @ W1)); bufB = bf16(relu(dinv*agg(bufA*sc) + b1))
    k_gemm<<<ntiles64, 256, 0, stream>>>(x0, Wt, dinv, bufA, sc, N_, 0);
    k_agg <<<(N_ + 15) / 16, 256, 0, stream>>>(bufA, sc, rowptr, esrc, dinv, b1, bufB, N_, 1, 1);
    // conv2: bufA,sc = int8(dinv * (bufB @ W2)), bf16 A-reads; bufB = f32 z
    k_gemm<<<ntiles64, 256, 0, stream>>>(bufB, Wt + 16384, dinv, bufA, sc, N_, 1);
    k_agg <<<(N_ + 15) / 16, 256, 0, stream>>>(bufA, sc, rowptr, esrc, dinv, b2, bufB, N_, 0, 0);

    // scoring: contiguous chunk ranges, W cached across same-relation chunks
    k_score_r<<<sgrid, 256, 0, stream>>>(bufB, relW, eidx, head, tail,
                                         roff, chkoff, outp, R_, cpb);
}

// Round 10
// 295.009 us; speedup vs baseline: 1.1208x; 1.0206x over previous
//
#include <hip/hip_runtime.h>
#include <hip/hip_bf16.h>

#define TD 128    // feature dim, fixed by problem
#define WS 136    // padded W-LDS row stride in bf16 (272 B: 16B-aligned, bank-uniform for b128)
#define SC_T 8    // triples per scoring block (R4 lesson: LDS > 80KB -> 1 block/CU cliff)
#define BKT_SH 7  // 128 nodes per CSR bucket (NB = ceil(N/128) <= 1024 for N <= 131072)
#define NBLK 256  // partition blocks for hist/scat passes

typedef __attribute__((ext_vector_type(8))) short bf16x8;   // 8 bf16 = 4 VGPR (MFMA A/B frag)
typedef __attribute__((ext_vector_type(4))) float f32x4;    // MFMA C/D frag

static __device__ __forceinline__ unsigned short f2bf(float f) {
    unsigned int u = __float_as_uint(f);
    u += 0x7fffu + ((u >> 16) & 1u);   // round-to-nearest-even
    return (unsigned short)(u >> 16);
}
static __device__ __forceinline__ float bf2f(unsigned short h) {
    return __uint_as_float((unsigned int)h << 16);
}

// ================= atomic-free CSR build =================
// R3: global atomic RMWs hit a ~24 op/ns chip floor with ~32B/op HBM write-through; replaced
// by LDS-histogram multi-split (zero global atomics). R7: wsplit fused in as extra blocks.

// pass 1: per-block bucket histogram (+ relation histogram) + fused W transpose/bf16 split.
__global__ __launch_bounds__(256) void kc_hist(const int* __restrict__ ei, int* __restrict__ bh,
                                               const int* __restrict__ rel, int* __restrict__ rcount,
                                               const float* __restrict__ W1, const float* __restrict__ W2,
                                               unsigned short* __restrict__ Wt,
                                               int E_, int ES_, int NB, int chunk, int rchunk) {
    __shared__ int lh[1024];
    __shared__ int rh[16];
    int t = threadIdx.x, blk = blockIdx.x;
    if (blk >= NBLK) {   // fused wsplit: blocks NBLK..NBLK+63, bf16-hi only (R7: lo planes dropped)
        int idx = (blk - NBLK) * 256 + t;   // 0..16383 = k*128+n (coalesced read)
        int k = idx >> 7, n = idx & 127;
        Wt[n * 128 + k] = f2bf(W1[idx]);
        Wt[16384 + n * 128 + k] = f2bf(W2[idx]);
        return;
    }
    for (int j = t; j < NB; j += 256) lh[j] = 0;
    if (t < 16) rh[t] = 0;
    __syncthreads();
    int e0 = blk * chunk, e1 = min(E_, e0 + chunk);
    for (int e = e0 + t; e < e1; e += 256)
        atomicAdd(&lh[ei[E_ + e] >> BKT_SH], 1);   // LDS atomic
    int r0 = blk * rchunk, r1 = min(ES_, r0 + rchunk);
    for (int e = r0 + t; e < r1; e += 256)
        atomicAdd(&rh[rel[e]], 1);                 // LDS atomic
    __syncthreads();
    for (int j = t; j < NB; j += 256) bh[(size_t)j * NBLK + blk] = lh[j];
    if (t < 16 && rh[t]) atomicAdd(&rcount[t], rh[t]);   // fire-and-forget, 16/block
}

// pass 2a: per bucket, exclusive scan over the NBLK block counts (in place); tot[b] = bucket size
__global__ __launch_bounds__(64) void kc_scanA(int* __restrict__ bh, int* __restrict__ tot, int NB) {
    int b = blockIdx.x, l = threadIdx.x;
    int* row = bh + (size_t)b * NBLK;
    int run = 0;
#pragma unroll
    for (int g = 0; g < NBLK / 64; ++g) {
        int v = row[g * 64 + l];
        int x = v;
#pragma unroll
        for (int off = 1; off < 64; off <<= 1) {
            int y = __shfl_up(x, off);
            if (l >= off) x += y;
        }
        row[g * 64 + l] = run + x - v;   // exclusive within bucket
        run += __shfl(x, 63);
    }
    if (l == 0) tot[b] = run;
}

// pass 2b: single-block exclusive scan of bucket totals -> boff[0..NB], rowptr[N] = E.
// R7: relation-offset scan + cursor init folded in (rcount final since kc_hist).
__global__ __launch_bounds__(256) void kc_scanB(const int* __restrict__ tot, int* __restrict__ boff,
                                                int NB, int* __restrict__ rowptrN,
                                                const int* __restrict__ rcount, int* __restrict__ roff,
                                                int* __restrict__ chunkoff, int* __restrict__ cursor, int nr) {
    __shared__ int wsum[4];
    int t = threadIdx.x;
    int base = t * 4;
    int a0 = (base     < NB) ? tot[base]     : 0;
    int a1 = (base + 1 < NB) ? tot[base + 1] : 0;
    int a2 = (base + 2 < NB) ? tot[base + 2] : 0;
    int a3 = (base + 3 < NB) ? tot[base + 3] : 0;
    int s1 = a0 + a1, s2 = s1 + a2, tt = s2 + a3;
    int lane = t & 63, wv = t >> 6;
    int x = tt;
#pragma unroll
    for (int off = 1; off < 64; off <<= 1) {
        int y = __shfl_up(x, off);
        if (lane >= off) x += y;
    }
    if (lane == 63) wsum[wv] = x;
    __syncthreads();
    int woff = 0;
    for (int w = 0; w < wv; ++w) woff += wsum[w];
    int excl = woff + x - tt;
    if (base     < NB) boff[base]     = excl;
    if (base + 1 < NB) boff[base + 1] = excl + a0;
    if (base + 2 < NB) boff[base + 2] = excl + s1;
    if (base + 3 < NB) boff[base + 3] = excl + s2;
    if (t == 255) { boff[NB] = woff + x; *rowptrN = woff + x; }
    if (t == 0) {   // relation offsets (serial, nr <= 16)
        int run = 0, crun = 0;
        for (int r = 0; r < nr; ++r) {
            roff[r] = run; chunkoff[r] = crun; cursor[r] = run;
            run += rcount[r]; crun += (rcount[r] + SC_T - 1) / SC_T;
        }
        roff[nr] = run; chunkoff[nr] = crun;
    }
}

// pass 3: scatter edges into bucket-grouped ebuf, packed (src<<7)|(dst&127). LDS-atomic ranks.
__global__ __launch_bounds__(256) void kc_scat(const int* __restrict__ ei, const int* __restrict__ bh,
                                               const int* __restrict__ boff, int* __restrict__ ebuf,
                                               int E_, int NB, int chunk) {
    __shared__ int lh[1024];
    int t = threadIdx.x, blk = blockIdx.x;
    for (int j = t; j < NB; j += 256) lh[j] = 0;
    __syncthreads();
    int e0 = blk * chunk, e1 = min(E_, e0 + chunk);
    for (int e = e0 + t; e < e1; e += 256) {
        int s = ei[e];
        int d = ei[E_ + e];
        int b = d >> BKT_SH;
        int lr = atomicAdd(&lh[b], 1);   // LDS atomic: rank within (block, bucket)
        int slot = boff[b] + bh[(size_t)b * NBLK + blk] + lr;
        ebuf[slot] = (s << BKT_SH) | (d & ((1 << BKT_SH) - 1));
    }
}

// pass 4: one block per bucket -> exact per-node counting sort. Writes rowptr, dinv, esrc.
__global__ __launch_bounds__(256) void kc_build(const int* __restrict__ ebuf, const int* __restrict__ boff,
                                                int* __restrict__ rowptr, float* __restrict__ dinv,
                                                int* __restrict__ esrc, int n) {
    __shared__ int hist[128], excl[128], cur[128];
    __shared__ int w0;
    int b = blockIdx.x, t = threadIdx.x;
    int node0 = b << BKT_SH;
    int s = boff[b], e = boff[b + 1];
    if (t < 128) { hist[t] = 0; cur[t] = 0; }
    __syncthreads();
    for (int i = s + t; i < e; i += 256)
        atomicAdd(&hist[ebuf[i] & 127], 1);   // LDS atomic
    __syncthreads();
    // scan the 128 counts (waves 0,1 active; uniform syncs)
    int v = (t < 128) ? hist[t] : 0;
    int lane = t & 63, wv = t >> 6;
    int x = v;
#pragma unroll
    for (int off = 1; off < 64; off <<= 1) {
        int y = __shfl_up(x, off);
        if (lane >= off) x += y;
    }
    if (t == 63) w0 = x;
    __syncthreads();
    if (t < 128) {
        int ex = x - v + (wv == 1 ? w0 : 0);
        excl[t] = ex;
        int node = node0 + t;
        if (node < n) {
            rowptr[node] = s + ex;
            dinv[node] = (v > 0) ? 1.0f / sqrtf((float)v) : 0.0f;
        }
    }
    __syncthreads();
    for (int i = s + t; i < e; i += 256) {
        int p = ebuf[i];
        int loc = p & 127;
        int lr = atomicAdd(&cur[loc], 1);   // LDS atomic
        esrc[s + excl[loc] + lr] = p >> BKT_SH;
    }
}

// ---------------- MFMA GEMM v9: bf16-only, 34KB LDS, optional bf16 A-input ----------------
// R7: hi/lo split dropped (int8 output quant dominates). R9: ibf16 path reads the A tile as
// bf16 directly (conv2's input bufB is written bf16 by k_agg — bit-identical, half the bytes).
__global__ __launch_bounds__(256, 4) void k_gemm(const void* __restrict__ Xv,
                                                 const unsigned short* __restrict__ Wth,
                                                 const float* __restrict__ scale,
                                                 unsigned char* __restrict__ out8,
                                                 float* __restrict__ scOut,
                                                 int nrows, int ibf16) {
    __shared__ __align__(16) unsigned short Wl[128 * WS];   // 34 KB; reused by epilogue transpose
    const int t = threadIdx.x;
    const int w = t >> 6;
    const int lane = t & 63;
    const int l15 = lane & 15;
    const int quad = lane >> 4;
    const int rbase = blockIdx.x * 64 + w * 16;   // wave's 16-row tile
    const int arow = rbase + l15;                 // this lane's A row
    const bool avalid = arow < nrows;

    // A fragments: bf16 direct loads (16B/kc) or f32 loads + convert (32B/kc)
    bf16x8 ah[4];
    const bf16x8 zero8 = {0, 0, 0, 0, 0, 0, 0, 0};
    if (ibf16) {
        const unsigned short* Xb = (const unsigned short*)Xv;
#pragma unroll
        for (int kc = 0; kc < 4; ++kc)
            ah[kc] = avalid ? *(const bf16x8*)(Xb + (size_t)arow * TD + kc * 32 + quad * 8) : zero8;
    } else {
        const float* X = (const float*)Xv;
        float4 xa[4][2];
#pragma unroll
        for (int kc = 0; kc < 4; ++kc) {
            const float* src = X + (size_t)arow * TD + kc * 32 + quad * 8;
            xa[kc][0] = avalid ? *(const float4*)src       : make_float4(0.f, 0.f, 0.f, 0.f);
            xa[kc][1] = avalid ? *(const float4*)(src + 4) : make_float4(0.f, 0.f, 0.f, 0.f);
        }
#pragma unroll
        for (int kc = 0; kc < 4; ++kc)
#pragma unroll
            for (int j = 0; j < 8; ++j) {
                float v = (j < 4) ? ((const float*)&xa[kc][0])[j] : ((const float*)&xa[kc][1])[j - 4];
                ah[kc][j] = (short)f2bf(v);
            }
    }

    // stage W-hi -> padded LDS: 2048 uint4, 8 per thread
    {
        const uint4* gh = (const uint4*)Wth;
#pragma unroll
        for (int it = 0; it < 8; ++it) {
            int idx = t + it * 256;            // 0..2047
            int n = idx >> 4, kg = idx & 15;   // row n, k-group kg (8 bf16 each)
            uint4 vh = gh[idx];
            *(uint4*)&Wl[n * WS + kg * 8] = vh;
        }
    }
    __syncthreads();

    f32x4 acc[8];
#pragma unroll
    for (int b = 0; b < 8; ++b) acc[b] = (f32x4){0.f, 0.f, 0.f, 0.f};

#pragma unroll
    for (int kc = 0; kc < 4; ++kc) {
        const int koff = kc * 32 + quad * 8;
#pragma unroll
        for (int b = 0; b < 8; ++b) {
            bf16x8 bh = *(const bf16x8*)&Wl[(b * 16 + l15) * WS + koff];
            acc[b] = __builtin_amdgcn_mfma_f32_16x16x32_bf16(ah[kc], bh, acc[b], 0, 0, 0);
        }
    }

    __syncthreads();   // all waves done reading Wl -> safe to reuse as transpose buffer

    // epilogue: m = acc*dinv; rowmax over 16 lanes; int8 quantize; LDS byte transpose
    {
        unsigned char* lds8 = (unsigned char*)&Wl[0];
        const int grow = rbase + quad * 4;        // multiple of 4; nrows % 4 == 0
        float4 s4 = make_float4(0.f, 0.f, 0.f, 0.f);
        if (grow < nrows) s4 = *(const float4*)&scale[grow];
        float rm[4];
#pragma unroll
        for (int j = 0; j < 4; ++j) {
            float sj = ((const float*)&s4)[j];
            float mx = 0.f;
#pragma unroll
            for (int b = 0; b < 8; ++b) {
                acc[b][j] *= sj;
                mx = fmaxf(mx, fabsf(acc[b][j]));
            }
            rm[j] = mx;
        }
#pragma unroll
        for (int m_ = 1; m_ < 16; m_ <<= 1)
#pragma unroll
            for (int j = 0; j < 4; ++j) rm[j] = fmaxf(rm[j], __shfl_xor(rm[j], m_));
        float inv[4];
#pragma unroll
        for (int j = 0; j < 4; ++j) inv[j] = rm[j] > 0.f ? 127.f / rm[j] : 0.f;
#pragma unroll
        for (int j = 0; j < 4; ++j) {
            int lrow = w * 16 + quad * 4 + j;
#pragma unroll
            for (int b = 0; b < 8; ++b) {
                int q = (int)rintf(acc[b][j] * inv[j]);
                lds8[lrow * 128 + b * 16 + l15] = (unsigned char)(signed char)q;
            }
        }
        if (l15 == 0 && grow < nrows)
            *(float4*)&scOut[grow] = make_float4(rm[0] * (1.f / 127.f), rm[1] * (1.f / 127.f),
                                                 rm[2] * (1.f / 127.f), rm[3] * (1.f / 127.f));
    }
    __syncthreads();
    {   // linear coalesced copy: 2048 dwords (64 rows x 128 B)
        const unsigned int* lds32 = (const unsigned int*)&Wl[0];
        unsigned int* g32 = (unsigned int*)out8;
#pragma unroll
        for (int k = 0; k < 8; ++k) {
            int idx = t + k * 256;
            int row = blockIdx.x * 64 + (idx >> 5);
            if (row < nrows) g32[(size_t)blockIdx.x * 2048 + idx] = lds32[idx];
        }
    }
}

// ---------------- CSR aggregation v4: int8 gather + optional needed-node filter ----------------
// R6: gather at the compulsory-miss floor for the nodes it processes. R10: agg#2's output z is
// read ONLY at scoring's head/tail rows (~45K of 100K distinct) — skip unneeded nodes entirely
// (stale bufB bytes are never read). ~55% of the final gather is dead work removed.
#define ACCI8(p, u, s) \
    p##0 = fmaf(s, (float)(signed char)(u.x      ), p##0); \
    p##1 = fmaf(s, (float)(signed char)(u.x >>  8), p##1); \
    p##2 = fmaf(s, (float)(signed char)(u.x >> 16), p##2); \
    p##3 = fmaf(s, (float)(signed char)(u.x >> 24), p##3); \
    p##4 = fmaf(s, (float)(signed char)(u.y      ), p##4); \
    p##5 = fmaf(s, (float)(signed char)(u.y >>  8), p##5); \
    p##6 = fmaf(s, (float)(signed char)(u.y >> 16), p##6); \
    p##7 = fmaf(s, (float)(signed char)(u.y >> 24), p##7);

__global__ __launch_bounds__(256) void k_agg(const unsigned char* __restrict__ hs8, const float* __restrict__ sc,
                                             const int* __restrict__ rowptr, const int* __restrict__ esrc,
                                             const float* __restrict__ dinv, const float* __restrict__ bias,
                                             void* __restrict__ outv, int n, int relu, int obf16,
                                             const unsigned char* __restrict__ need) {
    int node = blockIdx.x * 16 + (threadIdx.x >> 4);
    int lane = threadIdx.x & 15;
    if (node >= n) return;
    if (need && !need[node]) return;   // R10: node's output never read by scoring
    int s = rowptr[node], e = rowptr[node + 1];
    const uint2* h8 = (const uint2*)hs8;   // 16 lanes x 8B = one 128B int8 row
    float a0 = 0.f, a1 = 0.f, a2 = 0.f, a3 = 0.f, a4 = 0.f, a5 = 0.f, a6 = 0.f, a7 = 0.f;
    float c0 = 0.f, c1 = 0.f, c2 = 0.f, c3 = 0.f, c4 = 0.f, c5 = 0.f, c6 = 0.f, c7 = 0.f;
    int i = s;
    for (; i + 4 <= e; i += 4) {
        int s0 = esrc[i], s1 = esrc[i + 1], s2 = esrc[i + 2], s3 = esrc[i + 3];
        uint2 u0 = h8[(size_t)s0 * 16 + lane];
        uint2 u1 = h8[(size_t)s1 * 16 + lane];
        uint2 u2 = h8[(size_t)s2 * 16 + lane];
        uint2 u3 = h8[(size_t)s3 * 16 + lane];
        float f0 = sc[s0], f1 = sc[s1], f2 = sc[s2], f3 = sc[s3];
        ACCI8(a, u0, f0)
        ACCI8(c, u1, f1)
        ACCI8(a, u2, f2)
        ACCI8(c, u3, f3)
    }
    for (; i < e; ++i) {
        int s0 = esrc[i];
        uint2 u = h8[(size_t)s0 * 16 + lane];
        float f = sc[s0];
        ACCI8(a, u, f)
    }
    a0 += c0; a1 += c1; a2 += c2; a3 += c3;
    a4 += c4; a5 += c5; a6 += c6; a7 += c7;
    float di = dinv[node];
    float4 b0 = ((const float4*)bias)[lane * 2];
    float4 b1 = ((const float4*)bias)[lane * 2 + 1];
    float o0 = fmaf(di, a0, b0.x);
    float o1 = fmaf(di, a1, b0.y);
    float o2 = fmaf(di, a2, b0.z);
    float o3 = fmaf(di, a3, b0.w);
    float o4 = fmaf(di, a4, b1.x);
    float o5 = fmaf(di, a5, b1.y);
    float o6 = fmaf(di, a6, b1.z);
    float o7 = fmaf(di, a7, b1.w);
    if (relu) {
        o0 = fmaxf(o0, 0.f); o1 = fmaxf(o1, 0.f); o2 = fmaxf(o2, 0.f); o3 = fmaxf(o3, 0.f);
        o4 = fmaxf(o4, 0.f); o5 = fmaxf(o5, 0.f); o6 = fmaxf(o6, 0.f); o7 = fmaxf(o7, 0.f);
    }
    if (obf16) {
        unsigned int p0 = (unsigned int)f2bf(o0) | ((unsigned int)f2bf(o1) << 16);
        unsigned int p1 = (unsigned int)f2bf(o2) | ((unsigned int)f2bf(o3) << 16);
        unsigned int p2 = (unsigned int)f2bf(o4) | ((unsigned int)f2bf(o5) << 16);
        unsigned int p3 = (unsigned int)f2bf(o6) | ((unsigned int)f2bf(o7) << 16);
        ((uint4*)outv)[(size_t)node * 16 + lane] = make_uint4(p0, p1, p2, p3);
    } else {
        ((float4*)outv)[(size_t)node * 32 + lane * 2]     = make_float4(o0, o1, o2, o3);
        ((float4*)outv)[(size_t)node * 32 + lane * 2 + 1] = make_float4(o4, o5, o6, o7);
    }
}

// ---------------- relation bucketing + needed-node flags ----------------
__global__ __launch_bounds__(256) void k_bucket(const int* __restrict__ rel, int* __restrict__ cursor,
                                                int* __restrict__ eidx, const int* __restrict__ head,
                                                const int* __restrict__ tail, unsigned char* __restrict__ need,
                                                int es) {
    __shared__ int lh[16];
    __shared__ int lbase[16];
    int t = threadIdx.x;
    if (t < 16) lh[t] = 0;
    __syncthreads();
    int r[4], lr[4];
#pragma unroll
    for (int i = 0; i < 4; ++i) {
        int e = blockIdx.x * 1024 + i * 256 + t;
        if (e < es) {
            r[i] = rel[e];
            lr[i] = atomicAdd(&lh[r[i]], 1);   // LDS atomic: intra-block rank
            need[head[e]] = 1;                 // same-value byte stores: race-benign
            need[tail[e]] = 1;
        } else r[i] = -1;
    }
    __syncthreads();
    if (t < 16) lbase[t] = lh[t] ? atomicAdd(&cursor[t], lh[t]) : 0;   // reserve range
    __syncthreads();
#pragma unroll
    for (int i = 0; i < 4; ++i)
        if (r[i] >= 0) eidx[lbase[r[i]] + lr[i]] = blockIdx.x * 1024 + i * 256 + t;
}

// ---------------- batched scoring v3: contiguous chunk range per block ----------------
// R7 lesson: cooperative LDS staging of zh+zt (1 float4/thread) beats per-thread registers
// (8x redundant reads + VGPR-occupancy loss). W[r] cached across same-relation chunks.
__global__ __launch_bounds__(256) void k_score_r(const float* __restrict__ z, const float* __restrict__ relW,
                                                 const int* __restrict__ eidx, const int* __restrict__ head,
                                                 const int* __restrict__ tail, const int* __restrict__ roff,
                                                 const int* __restrict__ chunkoff, float* __restrict__ out,
                                                 int R_, int cpb) {
    __shared__ __align__(16) float Wl[TD * TD];      // 64 KB
    __shared__ __align__(16) float zhL[SC_T * TD];   // 4 KB
    __shared__ __align__(16) float ztL[SC_T * TD];   // 4 KB
    __shared__ int eids[SC_T];
    __shared__ int co[17], ro[17];
    __shared__ float red[4][SC_T];
    const int t = threadIdx.x;
    if (t < 17 && t <= R_) { co[t] = chunkoff[t]; ro[t] = roff[t]; }
    __syncthreads();
    const int nch = co[R_];                    // total real chunks
    int b = blockIdx.x * cpb;
    const int bend = min(nch, b + cpb);
    int r = 0, rprev = -1;
    for (; b < bend; ++b) {
        while (co[r + 1] <= b) ++r;            // monotone in b; uniform across block
        const int base = ro[r] + (b - co[r]) * SC_T;
        const int nt = min(SC_T, ro[r + 1] - base);
        if (t < SC_T) eids[t] = (t < nt) ? eidx[base + t] : -1;
        const bool newW = (r != rprev);
        rprev = r;
        __syncthreads();                       // eids visible; zhL free (post-compute barrier)
        {   // stage zh/zt: 256 float4, 1 per thread
            int tt = t >> 5, c4 = t & 31;
            float4 vh = make_float4(0.f, 0.f, 0.f, 0.f), vt = vh;
            int e = eids[tt];
            if (e >= 0) {
                vh = ((const float4*)(z + (size_t)head[e] * TD))[c4];
                vt = ((const float4*)(z + (size_t)tail[e] * TD))[c4];
            }
            ((float4*)(zhL + tt * TD))[c4] = vh;
            ((float4*)(ztL + tt * TD))[c4] = vt;
        }
        if (newW) {   // stage W[r]: 4096 float4 (only on relation change)
            const float4* W4 = (const float4*)(relW + (size_t)r * TD * TD);
            float4* Wl4 = (float4*)Wl;
#pragma unroll
            for (int i = 0; i < 16; ++i) Wl4[t + i * 256] = W4[t + i * 256];
        }
        __syncthreads();

        const int c  = (t & 31) * 4;    // cols c..c+3
        const int i0 = (t >> 5) * 16;   // 16-row i segment
        float4 acc[SC_T];
#pragma unroll
        for (int u = 0; u < SC_T; ++u) acc[u] = make_float4(0.f, 0.f, 0.f, 0.f);
#pragma unroll 4
        for (int i = i0; i < i0 + 16; ++i) {
            float4 wv = *(const float4*)&Wl[i * TD + c];
#pragma unroll
            for (int u = 0; u < SC_T; ++u) {
                float h = zhL[u * TD + i];
                acc[u].x = fmaf(h, wv.x, acc[u].x);
                acc[u].y = fmaf(h, wv.y, acc[u].y);
                acc[u].z = fmaf(h, wv.z, acc[u].z);
                acc[u].w = fmaf(h, wv.w, acc[u].w);
            }
        }
        float pth[SC_T];
#pragma unroll
        for (int u = 0; u < SC_T; ++u) {
            float4 z4 = *(const float4*)&ztL[u * TD + c];
            pth[u] = acc[u].x * z4.x + acc[u].y * z4.y + acc[u].z * z4.z + acc[u].w * z4.w;
        }
#pragma unroll
        for (int off = 32; off > 0; off >>= 1)
#pragma unroll
            for (int u = 0; u < SC_T; ++u) pth[u] += __shfl_down(pth[u], off);
        if ((t & 63) == 0) {
            int wv = t >> 6;
#pragma unroll
            for (int u = 0; u < SC_T; ++u) red[wv][u] = pth[u];
        }
        __syncthreads();
        if (t < SC_T) {
            int e = eids[t];
            if (e >= 0) out[e] = red[0][t] + red[1][t] + red[2][t] + red[3][t];
        }
    }
}

extern "C" void kernel_launch(void* const* d_in, const int* in_sizes, int n_in,
                              void* d_out, int out_size, void* d_ws, size_t ws_size,
                              hipStream_t stream) {
    const float* x0   = (const float*)d_in[0];
    const float* W1   = (const float*)d_in[1];
    const float* b1   = (const float*)d_in[2];
    const float* W2   = (const float*)d_in[3];
    const float* b2   = (const float*)d_in[4];
    const float* relW = (const float*)d_in[5];
    const int*   ei   = (const int*)d_in[6];
    const int*   rel  = (const int*)d_in[7];
    const int*   head = (const int*)d_in[8];
    const int*   tail = (const int*)d_in[9];
    float* outp = (float*)d_out;

    const int N_  = in_sizes[0] / TD;
    const int E_  = in_sizes[6] / 2;
    const int ES_ = in_sizes[7];
    const int R_  = in_sizes[5] / (TD * TD);
    const int ntiles64 = (N_ + 63) / 64;
    const int NB    = (N_ + (1 << BKT_SH) - 1) >> BKT_SH;   // <= 1024 for N <= 131072
    const int chunk  = (E_ + NBLK - 1) / NBLK;
    const int rchunk = (ES_ + NBLK - 1) / NBLK;
    const int maxch  = (ES_ + SC_T - 1) / SC_T + R_;        // upper bound on chunk count
    const int sgrid  = maxch < 512 ? maxch : 512;           // 2 blocks/CU
    const int cpb    = (maxch + sgrid - 1) / sgrid;         // chunks per block (contiguous)

    char* p = (char*)d_ws;
    auto alloc = [&](size_t bytes) { char* r = p; p += (bytes + 255) & ~(size_t)255; return r; };
    float*          dinv   = (float*)         alloc((size_t)N_ * 4);
    int*            rowptr = (int*)           alloc(((size_t)N_ + 1) * 4);
    int*            bh     = (int*)           alloc((size_t)NB * NBLK * 4);
    int*            tot    = (int*)           alloc((size_t)NB * 4);
    int*            boff   = (int*)           alloc(((size_t)NB + 1) * 4);
    int*            esrc   = (int*)           alloc((size_t)E_ * 4);
    unsigned short* Wt     = (unsigned short*)alloc((size_t)2 * 16384 * 2);   // W1h^T, W2h^T
    int*            rcount = (int*)           alloc((size_t)R_ * 4);
    int*            roff   = (int*)           alloc(((size_t)R_ + 1) * 4);
    int*            chkoff = (int*)           alloc(((size_t)R_ + 1) * 4);
    int*            cursor = (int*)           alloc((size_t)R_ * 4);
    int*            eidx   = (int*)           alloc((size_t)ES_ * 4);
    unsigned char*  need   = (unsigned char*) alloc((size_t)N_);              // scoring-needed flags
    unsigned char*  bufA   = (unsigned char*) alloc((size_t)N_ * TD);         // int8 messages
    float*          sc     = (float*)         alloc((size_t)N_ * 4);          // per-row scales
    float*          bufB   = (float*)         alloc((size_t)N_ * TD * 4);     // conv out (bf16 or f32)
    int*            ebuf   = (int*)bufA;   // alias: dead before first k_gemm writes bufA (E*4 <= N*TD)

    hipMemsetAsync(rcount, 0, (size_t)R_ * 4, stream);
    hipMemsetAsync(need, 0, (size_t)N_, stream);

    // atomic-free CSR: hist(+rel histo, +wsplit) -> scanA -> scanB(+roff) -> scatter -> build
    kc_hist <<<NBLK + 64, 256, 0, stream>>>(ei, bh, rel, rcount, W1, W2, Wt, E_, ES_, NB, chunk, rchunk);
    kc_scanA<<<NB, 64, 0, stream>>>(bh, tot, NB);
    kc_scanB<<<1, 256, 0, stream>>>(tot, boff, NB, rowptr + N_, rcount, roff, chkoff, cursor, R_);
    kc_scat <<<NBLK, 256, 0, stream>>>(ei, bh, boff, ebuf, E_, NB, chunk);
    kc_build<<<NB, 256, 0, stream>>>(ebuf, boff, rowptr, dinv, esrc, N_);

    k_bucket<<<(ES_ + 1023) / 1024, 256, 0, stream>>>(rel, cursor, eidx, head, tail, need, ES_);

    // conv1: bufA,sc = int8(dinv * (x0 @ W1)); bufB = bf16(relu(dinv*agg(bufA*sc) + b1))
    k_gemm<<<ntiles64, 256, 0, stream>>>(x0, Wt, dinv, bufA, sc, N_, 0);
    k_agg <<<(N_ + 15) / 16, 256, 0, stream>>>(bufA, sc, rowptr, esrc, dinv, b1, bufB, N_, 1, 1, (const unsigned char*)nullptr);
    // conv2: bufA,sc = int8(dinv * (bufB @ W2)), bf16 A-reads; bufB = f32 z (needed nodes only)
    k_gemm<<<ntiles64, 256, 0, stream>>>(bufB, Wt + 16384, dinv, bufA, sc, N_, 1);
    k_agg <<<(N_ + 15) / 16, 256, 0, stream>>>(bufA, sc, rowptr, esrc, dinv, b2, bufB, N_, 0, 0, need);

    // scoring: contiguous chunk ranges, W cached across same-relation chunks
    k_score_r<<<sgrid, 256, 0, stream>>>(bufB, relW, eidx, head, tail,
                                         roff, chkoff, outp, R_, cpb);
}

// Round 12
// 286.051 us; speedup vs baseline: 1.1559x; 1.0313x over previous
//
#include <hip/hip_runtime.h>
#include <hip/hip_bf16.h>

#define TD 128    // feature dim, fixed by problem
#define WS 136    // padded W-LDS row stride in bf16 (272 B: 16B-aligned, bank-uniform for b128)
#define SC_T 8    // triples per scoring block (R4 lesson: LDS > 80KB -> 1 block/CU cliff)
#define BKT_SH 7  // 128 nodes per CSR bucket (NB = ceil(N/128) <= 1024 for N <= 131072)
#define NBLK 256  // partition blocks for hist/scat passes

typedef __attribute__((ext_vector_type(8))) short bf16x8;   // 8 bf16 = 4 VGPR (MFMA A/B frag)
typedef __attribute__((ext_vector_type(4))) float f32x4;    // MFMA C/D frag

static __device__ __forceinline__ unsigned short f2bf(float f) {
    unsigned int u = __float_as_uint(f);
    u += 0x7fffu + ((u >> 16) & 1u);   // round-to-nearest-even
    return (unsigned short)(u >> 16);
}
static __device__ __forceinline__ float bf2f(unsigned short h) {
    return __uint_as_float((unsigned int)h << 16);
}

// ================= atomic-free CSR build =================
// R3: global atomic RMWs hit a ~24 op/ns chip floor; LDS-histogram multi-split instead.
// R11: dispatch-count reduction — R10 budget shows ~10us/dispatch overhead is ~half of total.
// memset(rcount) removed (rbh per-block array, summed in scanB); memset(need) removed (zeroed
// by extra kc_hist blocks); k_bucket fused into kc_scat as extra blocks. 14 -> 10 dispatches.

// pass 1: per-block bucket histogram + per-block relation counts + fused wsplit + need-zero.
__global__ __launch_bounds__(256) void kc_hist(const int* __restrict__ ei, int* __restrict__ bh,
                                               const int* __restrict__ rel, int* __restrict__ rbh,
                                               const float* __restrict__ W1, const float* __restrict__ W2,
                                               unsigned short* __restrict__ Wt,
                                               unsigned char* __restrict__ need, int N_,
                                               int E_, int ES_, int NB, int chunk, int rchunk) {
    __shared__ int lh[1024];
    __shared__ int rh[16];
    int t = threadIdx.x, blk = blockIdx.x;
    if (blk >= NBLK + 64) {   // need-zero blocks (stream-ordered before kc_scat's bucket writes)
        int i4 = (blk - NBLK - 64) * 256 + t;   // uint4 index; alloc padding absorbs tail
        if (i4 * 16 < N_) ((uint4*)need)[i4] = make_uint4(0u, 0u, 0u, 0u);
        return;
    }
    if (blk >= NBLK) {   // fused wsplit: blocks NBLK..NBLK+63, bf16-hi only (R7)
        int idx = (blk - NBLK) * 256 + t;   // 0..16383 = k*128+n (coalesced read)
        int k = idx >> 7, n = idx & 127;
        Wt[n * 128 + k] = f2bf(W1[idx]);
        Wt[16384 + n * 128 + k] = f2bf(W2[idx]);
        return;
    }
    for (int j = t; j < NB; j += 256) lh[j] = 0;
    if (t < 16) rh[t] = 0;
    __syncthreads();
    int e0 = blk * chunk, e1 = min(E_, e0 + chunk);
    for (int e = e0 + t; e < e1; e += 256)
        atomicAdd(&lh[ei[E_ + e] >> BKT_SH], 1);   // LDS atomic
    int r0 = blk * rchunk, r1 = min(ES_, r0 + rchunk);
    for (int e = r0 + t; e < r1; e += 256)
        atomicAdd(&rh[rel[e]], 1);                 // LDS atomic
    __syncthreads();
    for (int j = t; j < NB; j += 256) bh[(size_t)j * NBLK + blk] = lh[j];
    if (t < 16) rbh[(size_t)t * NBLK + blk] = rh[t];   // unconditional: no init needed
}

// pass 2a: per bucket, exclusive scan over the NBLK block counts (in place); tot[b] = bucket size
__global__ __launch_bounds__(64) void kc_scanA(int* __restrict__ bh, int* __restrict__ tot, int NB) {
    int b = blockIdx.x, l = threadIdx.x;
    int* row = bh + (size_t)b * NBLK;
    int run = 0;
#pragma unroll
    for (int g = 0; g < NBLK / 64; ++g) {
        int v = row[g * 64 + l];
        int x = v;
#pragma unroll
        for (int off = 1; off < 64; off <<= 1) {
            int y = __shfl_up(x, off);
            if (l >= off) x += y;
        }
        row[g * 64 + l] = run + x - v;   // exclusive within bucket
        run += __shfl(x, 63);
    }
    if (l == 0) tot[b] = run;
}

// pass 2b: single-block scan of bucket totals -> boff; rowptr[N]=E; relation offsets from rbh.
__global__ __launch_bounds__(256) void kc_scanB(const int* __restrict__ tot, int* __restrict__ boff,
                                                int NB, int* __restrict__ rowptrN,
                                                const int* __restrict__ rbh, int* __restrict__ roff,
                                                int* __restrict__ chunkoff, int* __restrict__ cursor, int nr) {
    __shared__ int wsum[4];
    __shared__ int rseg[16][17];
    int t = threadIdx.x;
    {   // parallel reduce rbh[16][NBLK]: thread t sums 16 entries of relation t&15
        int rl = t & 15, seg = t >> 4;
        const int per = NBLK / 16;
        int ps = 0;
        for (int k = 0; k < per; ++k) ps += rbh[(size_t)rl * NBLK + seg * per + k];
        rseg[rl][seg] = ps;
    }
    int base = t * 4;
    int a0 = (base     < NB) ? tot[base]     : 0;
    int a1 = (base + 1 < NB) ? tot[base + 1] : 0;
    int a2 = (base + 2 < NB) ? tot[base + 2] : 0;
    int a3 = (base + 3 < NB) ? tot[base + 3] : 0;
    int s1 = a0 + a1, s2 = s1 + a2, tt = s2 + a3;
    int lane = t & 63, wv = t >> 6;
    int x = tt;
#pragma unroll
    for (int off = 1; off < 64; off <<= 1) {
        int y = __shfl_up(x, off);
        if (lane >= off) x += y;
    }
    if (lane == 63) wsum[wv] = x;
    __syncthreads();
    int woff = 0;
    for (int w = 0; w < wv; ++w) woff += wsum[w];
    int excl = woff + x - tt;
    if (base     < NB) boff[base]     = excl;
    if (base + 1 < NB) boff[base + 1] = excl + a0;
    if (base + 2 < NB) boff[base + 2] = excl + s1;
    if (base + 3 < NB) boff[base + 3] = excl + s2;
    if (t == 255) { boff[NB] = woff + x; *rowptrN = woff + x; }
    if (t == 0) {   // relation offsets (serial, nr <= 16)
        int run = 0, crun = 0;
        for (int r = 0; r < nr; ++r) {
            int rc = 0;
#pragma unroll
            for (int sg = 0; sg < 16; ++sg) rc += rseg[r][sg];
            roff[r] = run; chunkoff[r] = crun; cursor[r] = run;
            run += rc; crun += (rc + SC_T - 1) / SC_T;
        }
        roff[nr] = run; chunkoff[nr] = crun;
    }
}

// pass 3: scatter edges into bucket-grouped ebuf (blocks < NBLK) + fused relation bucketing
// (blocks >= NBLK: old k_bucket — needs cursor from scanB, writes disjoint eidx/need).
__global__ __launch_bounds__(256) void kc_scat(const int* __restrict__ ei, const int* __restrict__ bh,
                                               const int* __restrict__ boff, int* __restrict__ ebuf,
                                               int E_, int NB, int chunk,
                                               const int* __restrict__ rel, int* __restrict__ cursor,
                                               int* __restrict__ eidx, const int* __restrict__ head,
                                               const int* __restrict__ tail, unsigned char* __restrict__ need,
                                               int ES_) {
    __shared__ int lh[1024];
    __shared__ int lbase[16];
    int t = threadIdx.x, blk = blockIdx.x;
    if (blk >= NBLK) {   // fused k_bucket
        int b2 = blk - NBLK;
        if (t < 16) lh[t] = 0;
        __syncthreads();
        int r[4], lr[4];
#pragma unroll
        for (int i = 0; i < 4; ++i) {
            int e = b2 * 1024 + i * 256 + t;
            if (e < ES_) {
                r[i] = rel[e];
                lr[i] = atomicAdd(&lh[r[i]], 1);   // LDS atomic: intra-block rank
                need[head[e]] = 1;                 // same-value byte stores: race-benign
                need[tail[e]] = 1;
            } else r[i] = -1;
        }
        __syncthreads();
        if (t < 16) lbase[t] = lh[t] ? atomicAdd(&cursor[t], lh[t]) : 0;   // reserve range
        __syncthreads();
#pragma unroll
        for (int i = 0; i < 4; ++i)
            if (r[i] >= 0) eidx[lbase[r[i]] + lr[i]] = b2 * 1024 + i * 256 + t;
        return;
    }
    for (int j = t; j < NB; j += 256) lh[j] = 0;
    __syncthreads();
    int e0 = blk * chunk, e1 = min(E_, e0 + chunk);
    for (int e = e0 + t; e < e1; e += 256) {
        int s = ei[e];
        int d = ei[E_ + e];
        int b = d >> BKT_SH;
        int lr = atomicAdd(&lh[b], 1);   // LDS atomic: rank within (block, bucket)
        int slot = boff[b] + bh[(size_t)b * NBLK + blk] + lr;
        ebuf[slot] = (s << BKT_SH) | (d & ((1 << BKT_SH) - 1));
    }
}

// pass 4: one block per bucket -> exact per-node counting sort. Writes rowptr, dinv, esrc.
__global__ __launch_bounds__(256) void kc_build(const int* __restrict__ ebuf, const int* __restrict__ boff,
                                                int* __restrict__ rowptr, float* __restrict__ dinv,
                                                int* __restrict__ esrc, int n) {
    __shared__ int hist[128], excl[128], cur[128];
    __shared__ int w0;
    int b = blockIdx.x, t = threadIdx.x;
    int node0 = b << BKT_SH;
    int s = boff[b], e = boff[b + 1];
    if (t < 128) { hist[t] = 0; cur[t] = 0; }
    __syncthreads();
    for (int i = s + t; i < e; i += 256)
        atomicAdd(&hist[ebuf[i] & 127], 1);   // LDS atomic
    __syncthreads();
    // scan the 128 counts (waves 0,1 active; uniform syncs)
    int v = (t < 128) ? hist[t] : 0;
    int lane = t & 63, wv = t >> 6;
    int x = v;
#pragma unroll
    for (int off = 1; off < 64; off <<= 1) {
        int y = __shfl_up(x, off);
        if (lane >= off) x += y;
    }
    if (t == 63) w0 = x;
    __syncthreads();
    if (t < 128) {
        int ex = x - v + (wv == 1 ? w0 : 0);
        excl[t] = ex;
        int node = node0 + t;
        if (node < n) {
            rowptr[node] = s + ex;
            dinv[node] = (v > 0) ? 1.0f / sqrtf((float)v) : 0.0f;
        }
    }
    __syncthreads();
    for (int i = s + t; i < e; i += 256) {
        int p = ebuf[i];
        int loc = p & 127;
        int lr = atomicAdd(&cur[loc], 1);   // LDS atomic
        esrc[s + excl[loc] + lr] = p >> BKT_SH;
    }
}

// ---------------- MFMA GEMM v9: bf16-only, 34KB LDS, optional bf16 A-input ----------------
// R7: hi/lo split dropped (int8 output quant dominates). R9: ibf16 path reads the A tile as
// bf16 directly (conv2's input bufB is written bf16 by k_agg — bit-identical, half the bytes).
__global__ __launch_bounds__(256, 4) void k_gemm(const void* __restrict__ Xv,
                                                 const unsigned short* __restrict__ Wth,
                                                 const float* __restrict__ scale,
                                                 unsigned char* __restrict__ out8,
                                                 float* __restrict__ scOut,
                                                 int nrows, int ibf16) {
    __shared__ __align__(16) unsigned short Wl[128 * WS];   // 34 KB; reused by epilogue transpose
    const int t = threadIdx.x;
    const int w = t >> 6;
    const int lane = t & 63;
    const int l15 = lane & 15;
    const int quad = lane >> 4;
    const int rbase = blockIdx.x * 64 + w * 16;   // wave's 16-row tile
    const int arow = rbase + l15;                 // this lane's A row
    const bool avalid = arow < nrows;

    // A fragments: bf16 direct loads (16B/kc) or f32 loads + convert (32B/kc)
    bf16x8 ah[4];
    const bf16x8 zero8 = {0, 0, 0, 0, 0, 0, 0, 0};
    if (ibf16) {
        const unsigned short* Xb = (const unsigned short*)Xv;
#pragma unroll
        for (int kc = 0; kc < 4; ++kc)
            ah[kc] = avalid ? *(const bf16x8*)(Xb + (size_t)arow * TD + kc * 32 + quad * 8) : zero8;
    } else {
        const float* X = (const float*)Xv;
        float4 xa[4][2];
#pragma unroll
        for (int kc = 0; kc < 4; ++kc) {
            const float* src = X + (size_t)arow * TD + kc * 32 + quad * 8;
            xa[kc][0] = avalid ? *(const float4*)src       : make_float4(0.f, 0.f, 0.f, 0.f);
            xa[kc][1] = avalid ? *(const float4*)(src + 4) : make_float4(0.f, 0.f, 0.f, 0.f);
        }
#pragma unroll
        for (int kc = 0; kc < 4; ++kc)
#pragma unroll
            for (int j = 0; j < 8; ++j) {
                float v = (j < 4) ? ((const float*)&xa[kc][0])[j] : ((const float*)&xa[kc][1])[j - 4];
                ah[kc][j] = (short)f2bf(v);
            }
    }

    // stage W-hi -> padded LDS: 2048 uint4, 8 per thread
    {
        const uint4* gh = (const uint4*)Wth;
#pragma unroll
        for (int it = 0; it < 8; ++it) {
            int idx = t + it * 256;            // 0..2047
            int n = idx >> 4, kg = idx & 15;   // row n, k-group kg (8 bf16 each)
            uint4 vh = gh[idx];
            *(uint4*)&Wl[n * WS + kg * 8] = vh;
        }
    }
    __syncthreads();

    f32x4 acc[8];
#pragma unroll
    for (int b = 0; b < 8; ++b) acc[b] = (f32x4){0.f, 0.f, 0.f, 0.f};

#pragma unroll
    for (int kc = 0; kc < 4; ++kc) {
        const int koff = kc * 32 + quad * 8;
#pragma unroll
        for (int b = 0; b < 8; ++b) {
            bf16x8 bh = *(const bf16x8*)&Wl[(b * 16 + l15) * WS + koff];
            acc[b] = __builtin_amdgcn_mfma_f32_16x16x32_bf16(ah[kc], bh, acc[b], 0, 0, 0);
        }
    }

    __syncthreads();   // all waves done reading Wl -> safe to reuse as transpose buffer

    // epilogue: m = acc*dinv; rowmax over 16 lanes; int8 quantize; LDS byte transpose
    {
        unsigned char* lds8 = (unsigned char*)&Wl[0];
        const int grow = rbase + quad * 4;        // multiple of 4; nrows % 4 == 0
        float4 s4 = make_float4(0.f, 0.f, 0.f, 0.f);
        if (grow < nrows) s4 = *(const float4*)&scale[grow];
        float rm[4];
#pragma unroll
        for (int j = 0; j < 4; ++j) {
            float sj = ((const float*)&s4)[j];
            float mx = 0.f;
#pragma unroll
            for (int b = 0; b < 8; ++b) {
                acc[b][j] *= sj;
                mx = fmaxf(mx, fabsf(acc[b][j]));
            }
            rm[j] = mx;
        }
#pragma unroll
        for (int m_ = 1; m_ < 16; m_ <<= 1)
#pragma unroll
            for (int j = 0; j < 4; ++j) rm[j] = fmaxf(rm[j], __shfl_xor(rm[j], m_));
        float inv[4];
#pragma unroll
        for (int j = 0; j < 4; ++j) inv[j] = rm[j] > 0.f ? 127.f / rm[j] : 0.f;
#pragma unroll
        for (int j = 0; j < 4; ++j) {
            int lrow = w * 16 + quad * 4 + j;
#pragma unroll
            for (int b = 0; b < 8; ++b) {
                int q = (int)rintf(acc[b][j] * inv[j]);
                lds8[lrow * 128 + b * 16 + l15] = (unsigned char)(signed char)q;
            }
        }
        if (l15 == 0 && grow < nrows)
            *(float4*)&scOut[grow] = make_float4(rm[0] * (1.f / 127.f), rm[1] * (1.f / 127.f),
                                                 rm[2] * (1.f / 127.f), rm[3] * (1.f / 127.f));
    }
    __syncthreads();
    {   // linear coalesced copy: 2048 dwords (64 rows x 128 B)
        const unsigned int* lds32 = (const unsigned int*)&Wl[0];
        unsigned int* g32 = (unsigned int*)out8;
#pragma unroll
        for (int k = 0; k < 8; ++k) {
            int idx = t + k * 256;
            int row = blockIdx.x * 64 + (idx >> 5);
            if (row < nrows) g32[(size_t)blockIdx.x * 2048 + idx] = lds32[idx];
        }
    }
}

// ---------------- CSR aggregation v4: int8 gather + optional needed-node filter ----------------
// R6: gather at the compulsory-miss floor for the nodes it processes. R10: agg#2 skips nodes
// whose z row scoring never reads (~55% dead work removed; verified bit-identical absmax).
#define ACCI8(p, u, s) \
    p##0 = fmaf(s, (float)(signed char)(u.x      ), p##0); \
    p##1 = fmaf(s, (float)(signed char)(u.x >>  8), p##1); \
    p##2 = fmaf(s, (float)(signed char)(u.x >> 16), p##2); \
    p##3 = fmaf(s, (float)(signed char)(u.x >> 24), p##3); \
    p##4 = fmaf(s, (float)(signed char)(u.y      ), p##4); \
    p##5 = fmaf(s, (float)(signed char)(u.y >>  8), p##5); \
    p##6 = fmaf(s, (float)(signed char)(u.y >> 16), p##6); \
    p##7 = fmaf(s, (float)(signed char)(u.y >> 24), p##7);

__global__ __launch_bounds__(256) void k_agg(const unsigned char* __restrict__ hs8, const float* __restrict__ sc,
                                             const int* __restrict__ rowptr, const int* __restrict__ esrc,
                                             const float* __restrict__ dinv, const float* __restrict__ bias,
                                             void* __restrict__ outv, int n, int relu, int obf16,
                                             const unsigned char* __restrict__ need) {
    int node = blockIdx.x * 16 + (threadIdx.x >> 4);
    int lane = threadIdx.x & 15;
    if (node >= n) return;
    if (need && !need[node]) return;   // R10: node's output never read by scoring
    int s = rowptr[node], e = rowptr[node + 1];
    const uint2* h8 = (const uint2*)hs8;   // 16 lanes x 8B = one 128B int8 row
    float a0 = 0.f, a1 = 0.f, a2 = 0.f, a3 = 0.f, a4 = 0.f, a5 = 0.f, a6 = 0.f, a7 = 0.f;
    float c0 = 0.f, c1 = 0.f, c2 = 0.f, c3 = 0.f, c4 = 0.f, c5 = 0.f, c6 = 0.f, c7 = 0.f;
    int i = s;
    for (; i + 4 <= e; i += 4) {
        int s0 = esrc[i], s1 = esrc[i + 1], s2 = esrc[i + 2], s3 = esrc[i + 3];
        uint2 u0 = h8[(size_t)s0 * 16 + lane];
        uint2 u1 = h8[(size_t)s1 * 16 + lane];
        uint2 u2 = h8[(size_t)s2 * 16 + lane];
        uint2 u3 = h8[(size_t)s3 * 16 + lane];
        float f0 = sc[s0], f1 = sc[s1], f2 = sc[s2], f3 = sc[s3];
        ACCI8(a, u0, f0)
        ACCI8(c, u1, f1)
        ACCI8(a, u2, f2)
        ACCI8(c, u3, f3)
    }
    for (; i < e; ++i) {
        int s0 = esrc[i];
        uint2 u = h8[(size_t)s0 * 16 + lane];
        float f = sc[s0];
        ACCI8(a, u, f)
    }
    a0 += c0; a1 += c1; a2 += c2; a3 += c3;
    a4 += c4; a5 += c5; a6 += c6; a7 += c7;
    float di = dinv[node];
    float4 b0 = ((const float4*)bias)[lane * 2];
    float4 b1 = ((const float4*)bias)[lane * 2 + 1];
    float o0 = fmaf(di, a0, b0.x);
    float o1 = fmaf(di, a1, b0.y);
    float o2 = fmaf(di, a2, b0.z);
    float o3 = fmaf(di, a3, b0.w);
    float o4 = fmaf(di, a4, b1.x);
    float o5 = fmaf(di, a5, b1.y);
    float o6 = fmaf(di, a6, b1.z);
    float o7 = fmaf(di, a7, b1.w);
    if (relu) {
        o0 = fmaxf(o0, 0.f); o1 = fmaxf(o1, 0.f); o2 = fmaxf(o2, 0.f); o3 = fmaxf(o3, 0.f);
        o4 = fmaxf(o4, 0.f); o5 = fmaxf(o5, 0.f); o6 = fmaxf(o6, 0.f); o7 = fmaxf(o7, 0.f);
    }
    if (obf16) {
        unsigned int p0 = (unsigned int)f2bf(o0) | ((unsigned int)f2bf(o1) << 16);
        unsigned int p1 = (unsigned int)f2bf(o2) | ((unsigned int)f2bf(o3) << 16);
        unsigned int p2 = (unsigned int)f2bf(o4) | ((unsigned int)f2bf(o5) << 16);
        unsigned int p3 = (unsigned int)f2bf(o6) | ((unsigned int)f2bf(o7) << 16);
        ((uint4*)outv)[(size_t)node * 16 + lane] = make_uint4(p0, p1, p2, p3);
    } else {
        ((float4*)outv)[(size_t)node * 32 + lane * 2]     = make_float4(o0, o1, o2, o3);
        ((float4*)outv)[(size_t)node * 32 + lane * 2 + 1] = make_float4(o4, o5, o6, o7);
    }
}

// ---------------- batched scoring v3: contiguous chunk range per block ----------------
// R7 lesson: cooperative LDS staging of zh+zt (1 float4/thread) beats per-thread registers
// (8x redundant reads + VGPR-occupancy loss). W[r] cached across same-relation chunks.
__global__ __launch_bounds__(256) void k_score_r(const float* __restrict__ z, const float* __restrict__ relW,
                                                 const int* __restrict__ eidx, const int* __restrict__ head,
                                                 const int* __restrict__ tail, const int* __restrict__ roff,
                                                 const int* __restrict__ chunkoff, float* __restrict__ out,
                                                 int R_, int cpb) {
    __shared__ __align__(16) float Wl[TD * TD];      // 64 KB
    __shared__ __align__(16) float zhL[SC_T * TD];   // 4 KB
    __shared__ __align__(16) float ztL[SC_T * TD];   // 4 KB
    __shared__ int eids[SC_T];
    __shared__ int co[17], ro[17];
    __shared__ float red[4][SC_T];
    const int t = threadIdx.x;
    if (t < 17 && t <= R_) { co[t] = chunkoff[t]; ro[t] = roff[t]; }
    __syncthreads();
    const int nch = co[R_];                    // total real chunks
    int b = blockIdx.x * cpb;
    const int bend = min(nch, b + cpb);
    int r = 0, rprev = -1;
    for (; b < bend; ++b) {
        while (co[r + 1] <= b) ++r;            // monotone in b; uniform across block
        const int base = ro[r] + (b - co[r]) * SC_T;
        const int nt = min(SC_T, ro[r + 1] - base);
        if (t < SC_T) eids[t] = (t < nt) ? eidx[base + t] : -1;
        const bool newW = (r != rprev);
        rprev = r;
        __syncthreads();                       // eids visible; zhL free (post-compute barrier)
        {   // stage zh/zt: 256 float4, 1 per thread
            int tt = t >> 5, c4 = t & 31;
            float4 vh = make_float4(0.f, 0.f, 0.f, 0.f), vt = vh;
            int e = eids[tt];
            if (e >= 0) {
                vh = ((const float4*)(z + (size_t)head[e] * TD))[c4];
                vt = ((const float4*)(z + (size_t)tail[e] * TD))[c4];
            }
            ((float4*)(zhL + tt * TD))[c4] = vh;
            ((float4*)(ztL + tt * TD))[c4] = vt;
        }
        if (newW) {   // stage W[r]: 4096 float4 (only on relation change)
            const float4* W4 = (const float4*)(relW + (size_t)r * TD * TD);
            float4* Wl4 = (float4*)Wl;
#pragma unroll
            for (int i = 0; i < 16; ++i) Wl4[t + i * 256] = W4[t + i * 256];
        }
        __syncthreads();

        const int c  = (t & 31) * 4;    // cols c..c+3
        const int i0 = (t >> 5) * 16;   // 16-row i segment
        float4 acc[SC_T];
#pragma unroll
        for (int u = 0; u < SC_T; ++u) acc[u] = make_float4(0.f, 0.f, 0.f, 0.f);
#pragma unroll 4
        for (int i = i0; i < i0 + 16; ++i) {
            float4 wv = *(const float4*)&Wl[i * TD + c];
#pragma unroll
            for (int u = 0; u < SC_T; ++u) {
                float h = zhL[u * TD + i];
                acc[u].x = fmaf(h, wv.x, acc[u].x);
                acc[u].y = fmaf(h, wv.y, acc[u].y);
                acc[u].z = fmaf(h, wv.z, acc[u].z);
                acc[u].w = fmaf(h, wv.w, acc[u].w);
            }
        }
        float pth[SC_T];
#pragma unroll
        for (int u = 0; u < SC_T; ++u) {
            float4 z4 = *(const float4*)&ztL[u * TD + c];
            pth[u] = acc[u].x * z4.x + acc[u].y * z4.y + acc[u].z * z4.z + acc[u].w * z4.w;
        }
#pragma unroll
        for (int off = 32; off > 0; off >>= 1)
#pragma unroll
            for (int u = 0; u < SC_T; ++u) pth[u] += __shfl_down(pth[u], off);
        if ((t & 63) == 0) {
            int wv = t >> 6;
#pragma unroll
            for (int u = 0; u < SC_T; ++u) red[wv][u] = pth[u];
        }
        __syncthreads();
        if (t < SC_T) {
            int e = eids[t];
            if (e >= 0) out[e] = red[0][t] + red[1][t] + red[2][t] + red[3][t];
        }
    }
}

extern "C" void kernel_launch(void* const* d_in, const int* in_sizes, int n_in,
                              void* d_out, int out_size, void* d_ws, size_t ws_size,
                              hipStream_t stream) {
    const float* x0   = (const float*)d_in[0];
    const float* W1   = (const float*)d_in[1];
    const float* b1   = (const float*)d_in[2];
    const float* W2   = (const float*)d_in[3];
    const float* b2   = (const float*)d_in[4];
    const float* relW = (const float*)d_in[5];
    const int*   ei   = (const int*)d_in[6];
    const int*   rel  = (const int*)d_in[7];
    const int*   head = (const int*)d_in[8];
    const int*   tail = (const int*)d_in[9];
    float* outp = (float*)d_out;

    const int N_  = in_sizes[0] / TD;
    const int E_  = in_sizes[6] / 2;
    const int ES_ = in_sizes[7];
    const int R_  = in_sizes[5] / (TD * TD);
    const int ntiles64 = (N_ + 63) / 64;
    const int NB    = (N_ + (1 << BKT_SH) - 1) >> BKT_SH;   // <= 1024 for N <= 131072
    const int chunk  = (E_ + NBLK - 1) / NBLK;
    const int rchunk = (ES_ + NBLK - 1) / NBLK;
    const int nzb    = (N_ + 4095) / 4096;                  // need-zero blocks (4KB each)
    const int nbuck  = (ES_ + 1023) / 1024;                 // fused k_bucket blocks
    const int maxch  = (ES_ + SC_T - 1) / SC_T + R_;        // upper bound on chunk count
    const int sgrid  = maxch < 512 ? maxch : 512;           // 2 blocks/CU
    const int cpb    = (maxch + sgrid - 1) / sgrid;         // chunks per block (contiguous)

    char* p = (char*)d_ws;
    auto alloc = [&](size_t bytes) { char* r = p; p += (bytes + 255) & ~(size_t)255; return r; };
    float*          dinv   = (float*)         alloc((size_t)N_ * 4);
    int*            rowptr = (int*)           alloc(((size_t)N_ + 1) * 4);
    int*            bh     = (int*)           alloc((size_t)NB * NBLK * 4);
    int*            rbh    = (int*)           alloc((size_t)16 * NBLK * 4);   // per-block rel counts
    int*            tot    = (int*)           alloc((size_t)NB * 4);
    int*            boff   = (int*)           alloc(((size_t)NB + 1) * 4);
    int*            esrc   = (int*)           alloc((size_t)E_ * 4);
    unsigned short* Wt     = (unsigned short*)alloc((size_t)2 * 16384 * 2);   // W1h^T, W2h^T
    int*            roff   = (int*)           alloc(((size_t)R_ + 1) * 4);
    int*            chkoff = (int*)           alloc(((size_t)R_ + 1) * 4);
    int*            cursor = (int*)           alloc((size_t)R_ * 4);
    int*            eidx   = (int*)           alloc((size_t)ES_ * 4);
    unsigned char*  need   = (unsigned char*) alloc((size_t)N_ + 16);         // scoring-needed flags
    unsigned char*  bufA   = (unsigned char*) alloc((size_t)N_ * TD);         // int8 messages
    float*          sc     = (float*)         alloc((size_t)N_ * 4);          // per-row scales
    float*          bufB   = (float*)         alloc((size_t)N_ * TD * 4);     // conv out (bf16 or f32)
    int*            ebuf   = (int*)bufA;   // alias: dead before first k_gemm writes bufA (E*4 <= N*TD)

    // atomic-free CSR, zero memsets, 10 dispatches total:
    // hist(+relcounts,+wsplit,+need-zero) -> scanA -> scanB(+roff from rbh) ->
    // scat(+bucket) -> build -> gemm1 -> agg1 -> gemm2 -> agg2 -> score
    kc_hist <<<NBLK + 64 + nzb, 256, 0, stream>>>(ei, bh, rel, rbh, W1, W2, Wt, need, N_,
                                                  E_, ES_, NB, chunk, rchunk);
    kc_scanA<<<NB, 64, 0, stream>>>(bh, tot, NB);
    kc_scanB<<<1, 256, 0, stream>>>(tot, boff, NB, rowptr + N_, rbh, roff, chkoff, cursor, R_);
    kc_scat <<<NBLK + nbuck, 256, 0, stream>>>(ei, bh, boff, ebuf, E_, NB, chunk,
                                               rel, cursor, eidx, head, tail, need, ES_);
    kc_build<<<NB, 256, 0, stream>>>(ebuf, boff, rowptr, dinv, esrc, N_);

    // conv1: bufA,sc = int8(dinv * (x0 @ W1)); bufB = bf16(relu(dinv*agg(bufA*sc) + b1))
    k_gemm<<<ntiles64, 256, 0, stream>>>(x0, Wt, dinv, bufA, sc, N_, 0);
    k_agg <<<(N_ + 15) / 16, 256, 0, stream>>>(bufA, sc, rowptr, esrc, dinv, b1, bufB, N_, 1, 1, (const unsigned char*)nullptr);
    // conv2: bufA,sc = int8(dinv * (bufB @ W2)), bf16 A-reads; bufB = f32 z (needed nodes only)
    k_gemm<<<ntiles64, 256, 0, stream>>>(bufB, Wt + 16384, dinv, bufA, sc, N_, 1);
    k_agg <<<(N_ + 15) / 16, 256, 0, stream>>>(bufA, sc, rowptr, esrc, dinv, b2, bufB, N_, 0, 0, need);

    // scoring: contiguous chunk ranges, W cached across same-relation chunks
    k_score_r<<<sgrid, 256, 0, stream>>>(bufB, relW, eidx, head, tail,
                                         roff, chkoff, outp, R_, cpb);
}